// Round 1
// baseline (1343.601 us; speedup 1.0000x reference)
//
#include <hip/hip_runtime.h>
#include <hip/hip_bf16.h>

#define N_ITEM 100000
#define N_USER 50000
#define DD 128
#define E1N 500000
#define E2N 250000

// ---------------- workspace layout (bytes) ----------------
static constexpr size_t OFF_STATS = 0;        // 512 f32: sum_i,sq_i,sum_u,sq_u
static constexpr size_t OFF_SCALE = 2048;     // 512 f32: scale_i,bias_i,scale_u,bias_u
static constexpr size_t OFF_M     = 4096;     // 8 f32: per-head safe max
static constexpr size_t OFF_WT    = 8192;     // 8 transposed 128x128 f32 weights
static constexpr size_t SZ_WT     = 8ull * 16384ull * 4ull;
static constexpr size_t SZ_ITEM   = (size_t)N_ITEM * 128 * 2;   // bf16
static constexpr size_t SZ_USER   = (size_t)N_USER * 128 * 2;   // bf16
static constexpr size_t OFF_Q1   = OFF_WT + SZ_WT;
static constexpr size_t OFF_K1   = OFF_Q1 + SZ_ITEM;
static constexpr size_t OFF_V1   = OFF_K1 + SZ_ITEM;
static constexpr size_t OFF_K2   = OFF_V1 + SZ_ITEM;
static constexpr size_t OFF_SELF = OFF_K2 + SZ_ITEM;
static constexpr size_t OFF_Q2   = OFF_SELF + SZ_ITEM;
static constexpr size_t OFF_V2   = OFF_Q2 + SZ_USER;
static constexpr size_t OFF_EX   = OFF_V2 + SZ_USER;                 // f32 [E,8]
static constexpr size_t OFF_S    = OFF_EX + (size_t)(E1N + E2N) * 8 * 4; // f32 [N_ITEM,8]
static constexpr size_t OFF_AGG  = OFF_S + (size_t)N_ITEM * 8 * 4;   // f32 [N_ITEM,128]

// ---------------- helpers ----------------
__device__ __forceinline__ float bf2f(unsigned short u) {
    return __uint_as_float(((unsigned)u) << 16);
}
__device__ __forceinline__ unsigned short f2bf(float f) {
    unsigned u = __float_as_uint(f);
    u += 0x7fffu + ((u >> 16) & 1u);   // round-to-nearest-even
    return (unsigned short)(u >> 16);
}

struct P8 { const float* p[8]; };

// ---------------- weight transpose: Wt[k*128+c] = W[c*128+k] ----------------
__global__ __launch_bounds__(256) void transpose_w(P8 src, float* __restrict__ dst) {
    int m = blockIdx.y;
    int i = blockIdx.x * 256 + threadIdx.x;   // 0..16383
    int k = i >> 7, c = i & 127;
    dst[m * 16384 + i] = src.p[m][c * 128 + k];
}

// ---------------- BN stats: per-column sum/sumsq ----------------
__global__ __launch_bounds__(256) void bn_stats(const float* __restrict__ ft_item,
                                                const float* __restrict__ ft_user,
                                                float* __restrict__ stats) {
    int type = blockIdx.y;
    const float* x = type ? ft_user : ft_item;
    int N = type ? N_USER : N_ITEM;
    float* sum = stats + type * 256;
    float* sq  = sum + 128;
    int c = threadIdx.x & 127;
    int half = threadIdx.x >> 7;
    int nb = gridDim.x;
    float s = 0.f, s2 = 0.f;
    for (int r = blockIdx.x * 2 + half; r < N; r += nb * 2) {
        float v = x[r * 128 + c];
        s += v; s2 += v * v;
    }
    __shared__ float ls[256], ls2[256];
    ls[threadIdx.x] = s; ls2[threadIdx.x] = s2;
    __syncthreads();
    if (half == 0) {
        s  = ls[c]  + ls[c + 128];
        s2 = ls2[c] + ls2[c + 128];
        atomicAdd(&sum[c], s);
        atomicAdd(&sq[c], s2);
    }
}

// ---------------- BN finalize + per-head safe max ----------------
__global__ __launch_bounds__(256) void bn_finalize(const float* __restrict__ g_i, const float* __restrict__ b_i,
                                                   const float* __restrict__ g_u, const float* __restrict__ b_u,
                                                   const float* __restrict__ ae1, const float* __restrict__ ae2,
                                                   float* __restrict__ wsf) {
    int t = threadIdx.x;
    float* stats = wsf;                 // floats
    float* scale = wsf + 512;           // OFF_SCALE
    float* M     = wsf + 1024;          // OFF_M
    {
        int type = t >> 7, c = t & 127;
        float N = type ? (float)N_USER : (float)N_ITEM;
        float su = stats[type * 256 + c];
        float sq = stats[type * 256 + 128 + c];
        float mu = su / N;
        float var = sq / N - mu * mu;
        float rstd = rsqrtf(var + 1e-5f);
        float g = type ? g_u[c] : g_i[c];
        float b = type ? b_u[c] : b_i[c];
        scale[type * 256 + c]       = g * rstd;
        scale[type * 256 + 128 + c] = b - mu * g * rstd;
    }
    if (t < 8) {
        float m1 = 0.f, m2 = 0.f;
        for (int j = 0; j < 16; j++) {
            m1 += fmaxf(ae1[t * 16 + j], 0.f);
            m2 += fmaxf(ae2[t * 16 + j], 0.f);
        }
        M[t] = fmaxf(m1, m2);   // uniform shift per head across both etypes
    }
}

// ---------------- fused BN-apply + NMAT GEMMs (f32 VALU, bf16 out) ----------------
struct TArgs {
    const float* x;
    const float* bias0;          // bias for matrix 0 only (q), may be null
    int N;
    int scaleOff;                // 0 item, 256 user (floats into scale region)
    int wtIdx[5];
    unsigned short* out[5];
};

template <int NMAT>
__global__ __launch_bounds__(256) void transform_kernel(TArgs args, char* __restrict__ ws) {
    __shared__ float xs[64][128];
    const float* scaleb = (const float*)(ws + OFF_SCALE) + args.scaleOff;
    const float* wtbase = (const float*)(ws + OFF_WT);
    int tid = threadIdx.x;
    int row0 = blockIdx.x * 64;
    #pragma unroll
    for (int i = 0; i < 8; i++) {
        int fi = tid + i * 256;
        int r = fi >> 5, c4 = fi & 31;
        int gr = row0 + r;
        float4 v = make_float4(0.f, 0.f, 0.f, 0.f);
        if (gr < args.N) {
            v = ((const float4*)args.x)[gr * 32 + c4];
            float4 sc = ((const float4*)scaleb)[c4];
            float4 bi = ((const float4*)(scaleb + 128))[c4];
            v.x = fmaf(v.x, sc.x, bi.x);
            v.y = fmaf(v.y, sc.y, bi.y);
            v.z = fmaf(v.z, sc.z, bi.z);
            v.w = fmaf(v.w, sc.w, bi.w);
        }
        ((float4*)xs)[fi] = v;
    }
    __syncthreads();
    int ty = tid >> 5, tx = tid & 31;
    int c0 = tx * 4;
    #pragma unroll
    for (int m = 0; m < NMAT; m++) {
        const float* W = wtbase + args.wtIdx[m] * 16384;
        float acc[8][4];
        float4 binit = make_float4(0.f, 0.f, 0.f, 0.f);
        if (m == 0 && args.bias0) binit = ((const float4*)args.bias0)[tx];
        #pragma unroll
        for (int r = 0; r < 8; r++) {
            acc[r][0] = binit.x; acc[r][1] = binit.y; acc[r][2] = binit.z; acc[r][3] = binit.w;
        }
        for (int k = 0; k < 128; k += 4) {
            float4 w0 = *(const float4*)(W + (k + 0) * 128 + c0);
            float4 w1 = *(const float4*)(W + (k + 1) * 128 + c0);
            float4 w2 = *(const float4*)(W + (k + 2) * 128 + c0);
            float4 w3 = *(const float4*)(W + (k + 3) * 128 + c0);
            #pragma unroll
            for (int r = 0; r < 8; r++) {
                float4 x = *(const float4*)(&xs[ty * 8 + r][k]);
                float* a = acc[r];
                a[0] = fmaf(x.x, w0.x, a[0]); a[1] = fmaf(x.x, w0.y, a[1]); a[2] = fmaf(x.x, w0.z, a[2]); a[3] = fmaf(x.x, w0.w, a[3]);
                a[0] = fmaf(x.y, w1.x, a[0]); a[1] = fmaf(x.y, w1.y, a[1]); a[2] = fmaf(x.y, w1.z, a[2]); a[3] = fmaf(x.y, w1.w, a[3]);
                a[0] = fmaf(x.z, w2.x, a[0]); a[1] = fmaf(x.z, w2.y, a[1]); a[2] = fmaf(x.z, w2.z, a[2]); a[3] = fmaf(x.z, w2.w, a[3]);
                a[0] = fmaf(x.w, w3.x, a[0]); a[1] = fmaf(x.w, w3.y, a[1]); a[2] = fmaf(x.w, w3.z, a[2]); a[3] = fmaf(x.w, w3.w, a[3]);
            }
        }
        unsigned short* out = args.out[m];
        #pragma unroll
        for (int r = 0; r < 8; r++) {
            int gr = row0 + ty * 8 + r;
            if (gr < args.N) {
                ushort4 o;
                o.x = f2bf(acc[r][0]); o.y = f2bf(acc[r][1]); o.z = f2bf(acc[r][2]); o.w = f2bf(acc[r][3]);
                *(ushort4*)(out + gr * 128 + c0) = o;
            }
        }
    }
}

// ---------------- edge pass 1: scores -> exp -> segment sum ----------------
__global__ __launch_bounds__(256) void edge_pass1(const int* __restrict__ uid1, const int* __restrict__ vid1,
                                                  const int* __restrict__ cnt1,
                                                  const int* __restrict__ uid2, const int* __restrict__ vid2,
                                                  const float* __restrict__ emb,
                                                  const float* __restrict__ ae1, const float* __restrict__ ae2,
                                                  char* __restrict__ ws) {
    const unsigned short* q1 = (const unsigned short*)(ws + OFF_Q1);
    const unsigned short* k1 = (const unsigned short*)(ws + OFF_K1);
    const unsigned short* k2 = (const unsigned short*)(ws + OFF_K2);
    const unsigned short* q2 = (const unsigned short*)(ws + OFF_Q2);
    float* exb = (float*)(ws + OFF_EX);
    float* s   = (float*)(ws + OFF_S);
    const float* M = (const float*)(ws + OFF_M);
    int lane = threadIdx.x & 63;
    int h = lane >> 3;
    int d0 = lane << 1;
    float mh = M[h];
    float2 ae1v = *(const float2*)(ae1 + d0);
    float2 ae2v = *(const float2*)(ae2 + d0);
    int wave = (blockIdx.x * blockDim.x + threadIdx.x) >> 6;
    int nw = (gridDim.x * blockDim.x) >> 6;
    for (int e = wave; e < E1N + E2N; e += nw) {
        const unsigned short *qrow, *krow;
        int dst;
        float e0 = 0.f, e1 = 0.f;
        float2 ae;
        if (e < E1N) {
            int u = uid1[e]; dst = vid1[e]; int cn = cnt1[e];
            qrow = q1 + u * 128; krow = k1 + dst * 128;
            float2 ev = *(const float2*)(emb + cn * 128 + d0);
            e0 = ev.x; e1 = ev.y; ae = ae1v;
        } else {
            int ee = e - E1N;
            int u = uid2[ee]; dst = vid2[ee];
            qrow = q2 + u * 128; krow = k2 + dst * 128;
            ae = ae2v;
        }
        unsigned qp = *(const unsigned*)(qrow + d0);
        unsigned kp = *(const unsigned*)(krow + d0);
        float x0 = bf2f((unsigned short)(qp & 0xffffu)) + bf2f((unsigned short)(kp & 0xffffu)) + e0;
        float x1 = bf2f((unsigned short)(qp >> 16))     + bf2f((unsigned short)(kp >> 16))     + e1;
        float t = ae.x / (1.f + __expf(-x0)) + ae.y / (1.f + __expf(-x1));
        t += __shfl_down(t, 4);
        t += __shfl_down(t, 2);
        t += __shfl_down(t, 1);
        if ((lane & 7) == 0) {
            float ex = __expf(t - mh);
            exb[e * 8 + h] = ex;
            atomicAdd(&s[dst * 8 + h], ex);
        }
    }
}

// ---------------- edge pass 2: weighted scatter-sum ----------------
__global__ __launch_bounds__(256) void edge_pass2(const int* __restrict__ uid1, const int* __restrict__ vid1,
                                                  const int* __restrict__ uid2, const int* __restrict__ vid2,
                                                  char* __restrict__ ws) {
    const unsigned short* v1 = (const unsigned short*)(ws + OFF_V1);
    const unsigned short* v2 = (const unsigned short*)(ws + OFF_V2);
    const float* exb = (const float*)(ws + OFF_EX);
    const float* s   = (const float*)(ws + OFF_S);
    float* agg = (float*)(ws + OFF_AGG);
    int lane = threadIdx.x & 63;
    int h = lane >> 3;
    int d0 = lane << 1;
    int wave = (blockIdx.x * blockDim.x + threadIdx.x) >> 6;
    int nw = (gridDim.x * blockDim.x) >> 6;
    for (int e = wave; e < E1N + E2N; e += nw) {
        const unsigned short* vrow;
        int dst;
        if (e < E1N) { vrow = v1 + uid1[e] * 128; dst = vid1[e]; }
        else { int ee = e - E1N; vrow = v2 + uid2[ee] * 128; dst = vid2[ee]; }
        float a = exb[e * 8 + h] / s[dst * 8 + h];
        unsigned vp = *(const unsigned*)(vrow + d0);
        atomicAdd(&agg[dst * 128 + d0],     bf2f((unsigned short)(vp & 0xffffu)) * a);
        atomicAdd(&agg[dst * 128 + d0 + 1], bf2f((unsigned short)(vp >> 16)) * a);
    }
}

// ---------------- final: relu(agg @ Wagg.T + b + selfterm) ----------------
__global__ __launch_bounds__(256) void final_kernel(const float* __restrict__ b_agg,
                                                    float* __restrict__ out, char* __restrict__ ws) {
    __shared__ float xs[64][128];
    const float* agg = (const float*)(ws + OFF_AGG);
    const unsigned short* selft = (const unsigned short*)(ws + OFF_SELF);
    const float* W = (const float*)(ws + OFF_WT) + 7 * 16384;
    int tid = threadIdx.x;
    int row0 = blockIdx.x * 64;
    #pragma unroll
    for (int i = 0; i < 8; i++) {
        int fi = tid + i * 256;
        int r = fi >> 5, c4 = fi & 31;
        int gr = row0 + r;
        float4 v = make_float4(0.f, 0.f, 0.f, 0.f);
        if (gr < N_ITEM) v = ((const float4*)agg)[gr * 32 + c4];
        ((float4*)xs)[fi] = v;
    }
    __syncthreads();
    int ty = tid >> 5, tx = tid & 31;
    int c0 = tx * 4;
    float acc[8][4];
    float4 binit = ((const float4*)b_agg)[tx];
    #pragma unroll
    for (int r = 0; r < 8; r++) {
        acc[r][0] = binit.x; acc[r][1] = binit.y; acc[r][2] = binit.z; acc[r][3] = binit.w;
    }
    for (int k = 0; k < 128; k += 4) {
        float4 w0 = *(const float4*)(W + (k + 0) * 128 + c0);
        float4 w1 = *(const float4*)(W + (k + 1) * 128 + c0);
        float4 w2 = *(const float4*)(W + (k + 2) * 128 + c0);
        float4 w3 = *(const float4*)(W + (k + 3) * 128 + c0);
        #pragma unroll
        for (int r = 0; r < 8; r++) {
            float4 x = *(const float4*)(&xs[ty * 8 + r][k]);
            float* a = acc[r];
            a[0] = fmaf(x.x, w0.x, a[0]); a[1] = fmaf(x.x, w0.y, a[1]); a[2] = fmaf(x.x, w0.z, a[2]); a[3] = fmaf(x.x, w0.w, a[3]);
            a[0] = fmaf(x.y, w1.x, a[0]); a[1] = fmaf(x.y, w1.y, a[1]); a[2] = fmaf(x.y, w1.z, a[2]); a[3] = fmaf(x.y, w1.w, a[3]);
            a[0] = fmaf(x.z, w2.x, a[0]); a[1] = fmaf(x.z, w2.y, a[1]); a[2] = fmaf(x.z, w2.z, a[2]); a[3] = fmaf(x.z, w2.w, a[3]);
            a[0] = fmaf(x.w, w3.x, a[0]); a[1] = fmaf(x.w, w3.y, a[1]); a[2] = fmaf(x.w, w3.z, a[2]); a[3] = fmaf(x.w, w3.w, a[3]);
        }
    }
    #pragma unroll
    for (int r = 0; r < 8; r++) {
        int gr = row0 + ty * 8 + r;
        if (gr < N_ITEM) {
            ushort4 st = *(const ushort4*)(selft + gr * 128 + c0);
            float4 o;
            o.x = fmaxf(acc[r][0] + bf2f(st.x), 0.f);
            o.y = fmaxf(acc[r][1] + bf2f(st.y), 0.f);
            o.z = fmaxf(acc[r][2] + bf2f(st.z), 0.f);
            o.w = fmaxf(acc[r][3] + bf2f(st.w), 0.f);
            *(float4*)(out + gr * 128 + c0) = o;
        }
    }
}

// ---------------- host ----------------
extern "C" void kernel_launch(void* const* d_in, const int* in_sizes, int n_in,
                              void* d_out, int out_size, void* d_ws, size_t ws_size,
                              hipStream_t stream) {
    char* ws = (char*)d_ws;

    const float* ft_item = (const float*)d_in[0];
    const float* ft_user = (const float*)d_in[1];
    const float* bng_i = (const float*)d_in[2];
    const float* bnb_i = (const float*)d_in[3];
    const float* bng_u = (const float*)d_in[4];
    const float* bnb_u = (const float*)d_in[5];
    const float* Wq1 = (const float*)d_in[6];
    const float* bq1 = (const float*)d_in[7];
    const float* Wk1 = (const float*)d_in[8];
    const float* Wv1 = (const float*)d_in[9];
    const float* ae1 = (const float*)d_in[10];
    const float* emb = (const float*)d_in[11];
    const float* Wq2 = (const float*)d_in[12];
    const float* bq2 = (const float*)d_in[13];
    const float* Wk2 = (const float*)d_in[14];
    const float* Wv2 = (const float*)d_in[15];
    const float* ae2 = (const float*)d_in[16];
    const float* W_agg = (const float*)d_in[17];
    const float* b_agg = (const float*)d_in[18];
    const float* W_self = (const float*)d_in[19];
    const int* uid1 = (const int*)d_in[20];
    const int* vid1 = (const int*)d_in[21];
    const int* cnt1 = (const int*)d_in[22];
    const int* uid2 = (const int*)d_in[23];
    const int* vid2 = (const int*)d_in[24];
    float* out = (float*)d_out;

    // zero accumulators (ws is poisoned 0xAA before every launch)
    hipMemsetAsync(ws + OFF_STATS, 0, 2048, stream);
    hipMemsetAsync(ws + OFF_S, 0, (size_t)N_ITEM * 8 * 4, stream);
    hipMemsetAsync(ws + OFF_AGG, 0, (size_t)N_ITEM * 128 * 4, stream);

    // transpose weights: order q1,k1,v1,k2,self,q2,v2,agg
    P8 p8;
    p8.p[0] = Wq1; p8.p[1] = Wk1; p8.p[2] = Wv1; p8.p[3] = Wk2;
    p8.p[4] = W_self; p8.p[5] = Wq2; p8.p[6] = Wv2; p8.p[7] = W_agg;
    transpose_w<<<dim3(64, 8), 256, 0, stream>>>(p8, (float*)(ws + OFF_WT));

    bn_stats<<<dim3(256, 2), 256, 0, stream>>>(ft_item, ft_user, (float*)(ws + OFF_STATS));
    bn_finalize<<<1, 256, 0, stream>>>(bng_i, bnb_i, bng_u, bnb_u, ae1, ae2, (float*)ws);

    // item transforms: q1,k1,v1,k2,self
    TArgs ti;
    ti.x = ft_item; ti.bias0 = bq1; ti.N = N_ITEM; ti.scaleOff = 0;
    ti.wtIdx[0] = 0; ti.wtIdx[1] = 1; ti.wtIdx[2] = 2; ti.wtIdx[3] = 3; ti.wtIdx[4] = 4;
    ti.out[0] = (unsigned short*)(ws + OFF_Q1);
    ti.out[1] = (unsigned short*)(ws + OFF_K1);
    ti.out[2] = (unsigned short*)(ws + OFF_V1);
    ti.out[3] = (unsigned short*)(ws + OFF_K2);
    ti.out[4] = (unsigned short*)(ws + OFF_SELF);
    transform_kernel<5><<<(N_ITEM + 63) / 64, 256, 0, stream>>>(ti, ws);

    // user transforms: q2,v2
    TArgs tu;
    tu.x = ft_user; tu.bias0 = bq2; tu.N = N_USER; tu.scaleOff = 256;
    tu.wtIdx[0] = 5; tu.wtIdx[1] = 6; tu.wtIdx[2] = 0; tu.wtIdx[3] = 0; tu.wtIdx[4] = 0;
    tu.out[0] = (unsigned short*)(ws + OFF_Q2);
    tu.out[1] = (unsigned short*)(ws + OFF_V2);
    tu.out[2] = tu.out[3] = tu.out[4] = (unsigned short*)(ws + OFF_Q2);
    transform_kernel<2><<<(N_USER + 63) / 64, 256, 0, stream>>>(tu, ws);

    edge_pass1<<<4096, 256, 0, stream>>>(uid1, vid1, cnt1, uid2, vid2, emb, ae1, ae2, ws);
    edge_pass2<<<4096, 256, 0, stream>>>(uid1, vid1, uid2, vid2, ws);

    final_kernel<<<(N_ITEM + 63) / 64, 256, 0, stream>>>(b_agg, out, ws);
}

// Round 2
// 820.641 us; speedup vs baseline: 1.6373x; 1.6373x over previous
//
#include <hip/hip_runtime.h>
#include <hip/hip_bf16.h>

#define N_ITEM 100000
#define N_USER 50000
#define E1N 500000
#define E2N 250000
#define EALL (E1N + E2N)
#define NPAD 100352          // 98 * 1024, >= N_ITEM

// ---------------- workspace layout (bytes) ----------------
static constexpr size_t OFF_STATS = 0;        // 512 f32: sum_i,sq_i,sum_u,sq_u
static constexpr size_t OFF_SCALE = 2048;     // 512 f32: scale_i,bias_i,scale_u,bias_u
static constexpr size_t OFF_M     = 4096;     // 8 f32: per-head safe max
static constexpr size_t OFF_WT    = 8192;     // 8 transposed 128x128 f32 weights
static constexpr size_t SZ_WT     = 8ull * 16384ull * 4ull;
static constexpr size_t SZ_ITEM   = (size_t)N_ITEM * 128 * 2;   // bf16
static constexpr size_t SZ_USER   = (size_t)N_USER * 128 * 2;   // bf16
static constexpr size_t OFF_Q1   = OFF_WT + SZ_WT;
static constexpr size_t OFF_K1   = OFF_Q1 + SZ_ITEM;
static constexpr size_t OFF_V1   = OFF_K1 + SZ_ITEM;
static constexpr size_t OFF_K2   = OFF_V1 + SZ_ITEM;
static constexpr size_t OFF_SELF = OFF_K2 + SZ_ITEM;
static constexpr size_t OFF_Q2   = OFF_SELF + SZ_ITEM;
static constexpr size_t OFF_V2   = OFF_Q2 + SZ_USER;
// CSR region (replaces old exb/s buffers)
static constexpr size_t OFF_HIST   = OFF_V2 + SZ_USER;          // NPAD ints
static constexpr size_t OFF_START  = OFF_HIST + (size_t)NPAD * 4;
static constexpr size_t OFF_CURSOR = OFF_START + (size_t)NPAD * 4;
static constexpr size_t OFF_BSUM   = OFF_CURSOR + (size_t)NPAD * 4;  // 128 ints, pad 1KB
static constexpr size_t OFF_ORD    = OFF_BSUM + 1024;           // EALL int2 records
static constexpr size_t OFF_AGG    = OFF_ORD + (size_t)EALL * 8; // f32 [N_ITEM,128]

// ---------------- helpers ----------------
__device__ __forceinline__ float bf2f(unsigned short u) {
    return __uint_as_float(((unsigned)u) << 16);
}
__device__ __forceinline__ unsigned short f2bf(float f) {
    unsigned u = __float_as_uint(f);
    u += 0x7fffu + ((u >> 16) & 1u);   // round-to-nearest-even
    return (unsigned short)(u >> 16);
}

struct P8 { const float* p[8]; };

// ---------------- weight transpose: Wt[k*128+c] = W[c*128+k] ----------------
__global__ __launch_bounds__(256) void transpose_w(P8 src, float* __restrict__ dst) {
    int m = blockIdx.y;
    int i = blockIdx.x * 256 + threadIdx.x;   // 0..16383
    int k = i >> 7, c = i & 127;
    dst[m * 16384 + i] = src.p[m][c * 128 + k];
}

// ---------------- BN stats: per-column sum/sumsq ----------------
__global__ __launch_bounds__(256) void bn_stats(const float* __restrict__ ft_item,
                                                const float* __restrict__ ft_user,
                                                float* __restrict__ stats) {
    int type = blockIdx.y;
    const float* x = type ? ft_user : ft_item;
    int N = type ? N_USER : N_ITEM;
    float* sum = stats + type * 256;
    float* sq  = sum + 128;
    int c = threadIdx.x & 127;
    int half = threadIdx.x >> 7;
    int nb = gridDim.x;
    float s = 0.f, s2 = 0.f;
    for (int r = blockIdx.x * 2 + half; r < N; r += nb * 2) {
        float v = x[r * 128 + c];
        s += v; s2 += v * v;
    }
    __shared__ float ls[256], ls2[256];
    ls[threadIdx.x] = s; ls2[threadIdx.x] = s2;
    __syncthreads();
    if (half == 0) {
        s  = ls[c]  + ls[c + 128];
        s2 = ls2[c] + ls2[c + 128];
        atomicAdd(&sum[c], s);
        atomicAdd(&sq[c], s2);
    }
}

// ---------------- BN finalize + per-head safe max ----------------
__global__ __launch_bounds__(256) void bn_finalize(const float* __restrict__ g_i, const float* __restrict__ b_i,
                                                   const float* __restrict__ g_u, const float* __restrict__ b_u,
                                                   const float* __restrict__ ae1, const float* __restrict__ ae2,
                                                   float* __restrict__ wsf) {
    int t = threadIdx.x;
    float* stats = wsf;                 // floats
    float* scale = wsf + 512;           // OFF_SCALE
    float* M     = wsf + 1024;          // OFF_M
    {
        int type = t >> 7, c = t & 127;
        float N = type ? (float)N_USER : (float)N_ITEM;
        float su = stats[type * 256 + c];
        float sq = stats[type * 256 + 128 + c];
        float mu = su / N;
        float var = sq / N - mu * mu;
        float rstd = rsqrtf(var + 1e-5f);
        float g = type ? g_u[c] : g_i[c];
        float b = type ? b_u[c] : b_i[c];
        scale[type * 256 + c]       = g * rstd;
        scale[type * 256 + 128 + c] = b - mu * g * rstd;
    }
    if (t < 8) {
        float m1 = 0.f, m2 = 0.f;
        for (int j = 0; j < 16; j++) {
            m1 += fmaxf(ae1[t * 16 + j], 0.f);
            m2 += fmaxf(ae2[t * 16 + j], 0.f);
        }
        M[t] = fmaxf(m1, m2);   // uniform shift per head across both etypes
    }
}

// ---------------- fused BN-apply + NMAT GEMMs (f32 VALU, bf16 out) ----------------
struct TArgs {
    const float* x;
    const float* bias0;          // bias for matrix 0 only (q), may be null
    int N;
    int scaleOff;                // 0 item, 256 user (floats into scale region)
    int wtIdx[5];
    unsigned short* out[5];
};

template <int NMAT>
__global__ __launch_bounds__(256) void transform_kernel(TArgs args, char* __restrict__ ws) {
    __shared__ float xs[64][128];
    const float* scaleb = (const float*)(ws + OFF_SCALE) + args.scaleOff;
    const float* wtbase = (const float*)(ws + OFF_WT);
    int tid = threadIdx.x;
    int row0 = blockIdx.x * 64;
    #pragma unroll
    for (int i = 0; i < 8; i++) {
        int fi = tid + i * 256;
        int r = fi >> 5, c4 = fi & 31;
        int gr = row0 + r;
        float4 v = make_float4(0.f, 0.f, 0.f, 0.f);
        if (gr < args.N) {
            v = ((const float4*)args.x)[gr * 32 + c4];
            float4 sc = ((const float4*)scaleb)[c4];
            float4 bi = ((const float4*)(scaleb + 128))[c4];
            v.x = fmaf(v.x, sc.x, bi.x);
            v.y = fmaf(v.y, sc.y, bi.y);
            v.z = fmaf(v.z, sc.z, bi.z);
            v.w = fmaf(v.w, sc.w, bi.w);
        }
        ((float4*)xs)[fi] = v;
    }
    __syncthreads();
    int ty = tid >> 5, tx = tid & 31;
    int c0 = tx * 4;
    #pragma unroll
    for (int m = 0; m < NMAT; m++) {
        const float* W = wtbase + args.wtIdx[m] * 16384;
        float acc[8][4];
        float4 binit = make_float4(0.f, 0.f, 0.f, 0.f);
        if (m == 0 && args.bias0) binit = ((const float4*)args.bias0)[tx];
        #pragma unroll
        for (int r = 0; r < 8; r++) {
            acc[r][0] = binit.x; acc[r][1] = binit.y; acc[r][2] = binit.z; acc[r][3] = binit.w;
        }
        for (int k = 0; k < 128; k += 4) {
            float4 w0 = *(const float4*)(W + (k + 0) * 128 + c0);
            float4 w1 = *(const float4*)(W + (k + 1) * 128 + c0);
            float4 w2 = *(const float4*)(W + (k + 2) * 128 + c0);
            float4 w3 = *(const float4*)(W + (k + 3) * 128 + c0);
            #pragma unroll
            for (int r = 0; r < 8; r++) {
                float4 x = *(const float4*)(&xs[ty * 8 + r][k]);
                float* a = acc[r];
                a[0] = fmaf(x.x, w0.x, a[0]); a[1] = fmaf(x.x, w0.y, a[1]); a[2] = fmaf(x.x, w0.z, a[2]); a[3] = fmaf(x.x, w0.w, a[3]);
                a[0] = fmaf(x.y, w1.x, a[0]); a[1] = fmaf(x.y, w1.y, a[1]); a[2] = fmaf(x.y, w1.z, a[2]); a[3] = fmaf(x.y, w1.w, a[3]);
                a[0] = fmaf(x.z, w2.x, a[0]); a[1] = fmaf(x.z, w2.y, a[1]); a[2] = fmaf(x.z, w2.z, a[2]); a[3] = fmaf(x.z, w2.w, a[3]);
                a[0] = fmaf(x.w, w3.x, a[0]); a[1] = fmaf(x.w, w3.y, a[1]); a[2] = fmaf(x.w, w3.z, a[2]); a[3] = fmaf(x.w, w3.w, a[3]);
            }
        }
        unsigned short* out = args.out[m];
        #pragma unroll
        for (int r = 0; r < 8; r++) {
            int gr = row0 + ty * 8 + r;
            if (gr < args.N) {
                ushort4 o;
                o.x = f2bf(acc[r][0]); o.y = f2bf(acc[r][1]); o.z = f2bf(acc[r][2]); o.w = f2bf(acc[r][3]);
                *(ushort4*)(out + gr * 128 + c0) = o;
            }
        }
    }
}

// ---------------- CSR build ----------------
__global__ __launch_bounds__(256) void edge_hist(const int* __restrict__ vid1,
                                                 const int* __restrict__ vid2,
                                                 int* __restrict__ hist) {
    int e = blockIdx.x * 256 + threadIdx.x;
    if (e >= EALL) return;
    int dst = (e < E1N) ? vid1[e] : vid2[e - E1N];
    atomicAdd(&hist[dst], 1);
}

// 98 blocks x 1024: per-chunk exclusive scan + block totals
__global__ __launch_bounds__(1024) void scan_partial(const int* __restrict__ hist,
                                                     int* __restrict__ start,
                                                     int* __restrict__ bsum) {
    __shared__ int sd[1024];
    int t = threadIdx.x;
    int gid = blockIdx.x * 1024 + t;
    int v = hist[gid];
    sd[t] = v;
    __syncthreads();
    #pragma unroll
    for (int off = 1; off < 1024; off <<= 1) {
        int x = (t >= off) ? sd[t - off] : 0;
        __syncthreads();
        sd[t] += x;
        __syncthreads();
    }
    start[gid] = sd[t] - v;            // exclusive
    if (t == 1023) bsum[blockIdx.x] = sd[t];
}

// 1 block x 128: exclusive scan of 98 block totals
__global__ __launch_bounds__(128) void scan_top(int* __restrict__ bsum) {
    __shared__ int sd[128];
    int t = threadIdx.x;
    int v = (t < 98) ? bsum[t] : 0;
    sd[t] = v;
    __syncthreads();
    #pragma unroll
    for (int off = 1; off < 128; off <<= 1) {
        int x = (t >= off) ? sd[t - off] : 0;
        __syncthreads();
        sd[t] += x;
        __syncthreads();
    }
    if (t < 98) bsum[t] = sd[t] - v;   // exclusive
}

__global__ __launch_bounds__(1024) void scan_add(int* __restrict__ start,
                                                 int* __restrict__ cursor,
                                                 const int* __restrict__ bsum) {
    int t = threadIdx.x;
    int gid = blockIdx.x * 1024 + t;
    int s = start[gid] + bsum[blockIdx.x];
    start[gid] = s;
    cursor[gid] = s;
}

// scatter packed edge records: {src_row, cnt | -1}
__global__ __launch_bounds__(256) void edge_scatter(const int* __restrict__ uid1, const int* __restrict__ vid1,
                                                    const int* __restrict__ cnt1,
                                                    const int* __restrict__ uid2, const int* __restrict__ vid2,
                                                    int* __restrict__ cursor, int2* __restrict__ ord) {
    int e = blockIdx.x * 256 + threadIdx.x;
    if (e >= EALL) return;
    int2 rec;
    int dst;
    if (e < E1N) {
        rec.x = uid1[e]; rec.y = cnt1[e]; dst = vid1[e];
    } else {
        int ee = e - E1N;
        rec.x = uid2[ee]; rec.y = -1; dst = vid2[ee];
    }
    int pos = atomicAdd(&cursor[dst], 1);
    ord[pos] = rec;
}

// ---------------- fused edge phase: wave per dst, no atomics ----------------
__global__ __launch_bounds__(256) void edge_agg(const float* __restrict__ emb,
                                                const float* __restrict__ ae1, const float* __restrict__ ae2,
                                                char* __restrict__ ws) {
    const unsigned short* q1 = (const unsigned short*)(ws + OFF_Q1);
    const unsigned short* k1 = (const unsigned short*)(ws + OFF_K1);
    const unsigned short* v1 = (const unsigned short*)(ws + OFF_V1);
    const unsigned short* k2 = (const unsigned short*)(ws + OFF_K2);
    const unsigned short* q2 = (const unsigned short*)(ws + OFF_Q2);
    const unsigned short* v2 = (const unsigned short*)(ws + OFF_V2);
    const int* start = (const int*)(ws + OFF_START);
    const int2* ord = (const int2*)(ws + OFF_ORD);
    const float* M = (const float*)(ws + OFF_M);
    float* agg = (float*)(ws + OFF_AGG);

    int tid = threadIdx.x;
    int lane = tid & 63;
    int dst = blockIdx.x * 4 + (tid >> 6);
    if (dst >= N_ITEM) return;
    int h = lane >> 3;
    int d0 = lane << 1;

    float mh = M[h];
    float2 ae1v = *(const float2*)(ae1 + d0);
    float2 ae2v = *(const float2*)(ae2 + d0);
    // hoist dst-side k rows (one 4B load each per lane)
    unsigned k1p = *(const unsigned*)(k1 + dst * 128 + d0);
    unsigned k2p = *(const unsigned*)(k2 + dst * 128 + d0);
    float k1lo = bf2f((unsigned short)(k1p & 0xffffu)), k1hi = bf2f((unsigned short)(k1p >> 16));
    float k2lo = bf2f((unsigned short)(k2p & 0xffffu)), k2hi = bf2f((unsigned short)(k2p >> 16));

    int beg = start[dst], end = start[dst + 1];
    float acc0 = 0.f, acc1 = 0.f, s = 0.f;
    for (int i = beg; i < end; i++) {
        int2 rec = ord[i];
        bool t1 = rec.y >= 0;
        const unsigned short* qrow = (t1 ? q1 : q2) + (size_t)rec.x * 128;
        const unsigned short* vrow = (t1 ? v1 : v2) + (size_t)rec.x * 128;
        unsigned qp = *(const unsigned*)(qrow + d0);
        float x0 = bf2f((unsigned short)(qp & 0xffffu)) + (t1 ? k1lo : k2lo);
        float x1 = bf2f((unsigned short)(qp >> 16))     + (t1 ? k1hi : k2hi);
        float2 ae = t1 ? ae1v : ae2v;
        if (t1) {
            float2 ev = *(const float2*)(emb + rec.y * 128 + d0);
            x0 += ev.x; x1 += ev.y;
        }
        float t = ae.x / (1.f + __expf(-x0)) + ae.y / (1.f + __expf(-x1));
        // head-reduce across the 8 lanes owning this head's 16 dims
        t += __shfl_xor(t, 1);
        t += __shfl_xor(t, 2);
        t += __shfl_xor(t, 4);
        float ex = __expf(t - mh);
        s += ex;
        unsigned vp = *(const unsigned*)(vrow + d0);
        acc0 = fmaf(ex, bf2f((unsigned short)(vp & 0xffffu)), acc0);
        acc1 = fmaf(ex, bf2f((unsigned short)(vp >> 16)), acc1);
    }
    float inv = (s > 0.f) ? (1.f / s) : 0.f;
    float2 o = make_float2(acc0 * inv, acc1 * inv);
    *(float2*)(agg + (size_t)dst * 128 + d0) = o;
}

// ---------------- final: relu(agg @ Wagg.T + b + selfterm) ----------------
__global__ __launch_bounds__(256) void final_kernel(const float* __restrict__ b_agg,
                                                    float* __restrict__ out, char* __restrict__ ws) {
    __shared__ float xs[64][128];
    const float* agg = (const float*)(ws + OFF_AGG);
    const unsigned short* selft = (const unsigned short*)(ws + OFF_SELF);
    const float* W = (const float*)(ws + OFF_WT) + 7 * 16384;
    int tid = threadIdx.x;
    int row0 = blockIdx.x * 64;
    #pragma unroll
    for (int i = 0; i < 8; i++) {
        int fi = tid + i * 256;
        int r = fi >> 5, c4 = fi & 31;
        int gr = row0 + r;
        float4 v = make_float4(0.f, 0.f, 0.f, 0.f);
        if (gr < N_ITEM) v = ((const float4*)agg)[gr * 32 + c4];
        ((float4*)xs)[fi] = v;
    }
    __syncthreads();
    int ty = tid >> 5, tx = tid & 31;
    int c0 = tx * 4;
    float acc[8][4];
    float4 binit = ((const float4*)b_agg)[tx];
    #pragma unroll
    for (int r = 0; r < 8; r++) {
        acc[r][0] = binit.x; acc[r][1] = binit.y; acc[r][2] = binit.z; acc[r][3] = binit.w;
    }
    for (int k = 0; k < 128; k += 4) {
        float4 w0 = *(const float4*)(W + (k + 0) * 128 + c0);
        float4 w1 = *(const float4*)(W + (k + 1) * 128 + c0);
        float4 w2 = *(const float4*)(W + (k + 2) * 128 + c0);
        float4 w3 = *(const float4*)(W + (k + 3) * 128 + c0);
        #pragma unroll
        for (int r = 0; r < 8; r++) {
            float4 x = *(const float4*)(&xs[ty * 8 + r][k]);
            float* a = acc[r];
            a[0] = fmaf(x.x, w0.x, a[0]); a[1] = fmaf(x.x, w0.y, a[1]); a[2] = fmaf(x.x, w0.z, a[2]); a[3] = fmaf(x.x, w0.w, a[3]);
            a[0] = fmaf(x.y, w1.x, a[0]); a[1] = fmaf(x.y, w1.y, a[1]); a[2] = fmaf(x.y, w1.z, a[2]); a[3] = fmaf(x.y, w1.w, a[3]);
            a[0] = fmaf(x.z, w2.x, a[0]); a[1] = fmaf(x.z, w2.y, a[1]); a[2] = fmaf(x.z, w2.z, a[2]); a[3] = fmaf(x.z, w2.w, a[3]);
            a[0] = fmaf(x.w, w3.x, a[0]); a[1] = fmaf(x.w, w3.y, a[1]); a[2] = fmaf(x.w, w3.z, a[2]); a[3] = fmaf(x.w, w3.w, a[3]);
        }
    }
    #pragma unroll
    for (int r = 0; r < 8; r++) {
        int gr = row0 + ty * 8 + r;
        if (gr < N_ITEM) {
            ushort4 st = *(const ushort4*)(selft + gr * 128 + c0);
            float4 o;
            o.x = fmaxf(acc[r][0] + bf2f(st.x), 0.f);
            o.y = fmaxf(acc[r][1] + bf2f(st.y), 0.f);
            o.z = fmaxf(acc[r][2] + bf2f(st.z), 0.f);
            o.w = fmaxf(acc[r][3] + bf2f(st.w), 0.f);
            *(float4*)(out + gr * 128 + c0) = o;
        }
    }
}

// ---------------- host ----------------
extern "C" void kernel_launch(void* const* d_in, const int* in_sizes, int n_in,
                              void* d_out, int out_size, void* d_ws, size_t ws_size,
                              hipStream_t stream) {
    char* ws = (char*)d_ws;

    const float* ft_item = (const float*)d_in[0];
    const float* ft_user = (const float*)d_in[1];
    const float* bng_i = (const float*)d_in[2];
    const float* bnb_i = (const float*)d_in[3];
    const float* bng_u = (const float*)d_in[4];
    const float* bnb_u = (const float*)d_in[5];
    const float* Wq1 = (const float*)d_in[6];
    const float* bq1 = (const float*)d_in[7];
    const float* Wk1 = (const float*)d_in[8];
    const float* Wv1 = (const float*)d_in[9];
    const float* ae1 = (const float*)d_in[10];
    const float* emb = (const float*)d_in[11];
    const float* Wq2 = (const float*)d_in[12];
    const float* bq2 = (const float*)d_in[13];
    const float* Wk2 = (const float*)d_in[14];
    const float* Wv2 = (const float*)d_in[15];
    const float* ae2 = (const float*)d_in[16];
    const float* W_agg = (const float*)d_in[17];
    const float* b_agg = (const float*)d_in[18];
    const float* W_self = (const float*)d_in[19];
    const int* uid1 = (const int*)d_in[20];
    const int* vid1 = (const int*)d_in[21];
    const int* cnt1 = (const int*)d_in[22];
    const int* uid2 = (const int*)d_in[23];
    const int* vid2 = (const int*)d_in[24];
    float* out = (float*)d_out;

    // zero accumulators (ws is poisoned 0xAA before every launch)
    hipMemsetAsync(ws + OFF_STATS, 0, 2048, stream);
    hipMemsetAsync(ws + OFF_HIST, 0, (size_t)NPAD * 4, stream);

    // transpose weights: order q1,k1,v1,k2,self,q2,v2,agg
    P8 p8;
    p8.p[0] = Wq1; p8.p[1] = Wk1; p8.p[2] = Wv1; p8.p[3] = Wk2;
    p8.p[4] = W_self; p8.p[5] = Wq2; p8.p[6] = Wv2; p8.p[7] = W_agg;
    transpose_w<<<dim3(64, 8), 256, 0, stream>>>(p8, (float*)(ws + OFF_WT));

    bn_stats<<<dim3(256, 2), 256, 0, stream>>>(ft_item, ft_user, (float*)(ws + OFF_STATS));
    bn_finalize<<<1, 256, 0, stream>>>(bng_i, bnb_i, bng_u, bnb_u, ae1, ae2, (float*)ws);

    // CSR build (overlaps transforms' dependencies only through stream order)
    edge_hist<<<(EALL + 255) / 256, 256, 0, stream>>>(vid1, vid2, (int*)(ws + OFF_HIST));
    scan_partial<<<98, 1024, 0, stream>>>((int*)(ws + OFF_HIST), (int*)(ws + OFF_START), (int*)(ws + OFF_BSUM));
    scan_top<<<1, 128, 0, stream>>>((int*)(ws + OFF_BSUM));
    scan_add<<<98, 1024, 0, stream>>>((int*)(ws + OFF_START), (int*)(ws + OFF_CURSOR), (int*)(ws + OFF_BSUM));
    edge_scatter<<<(EALL + 255) / 256, 256, 0, stream>>>(uid1, vid1, cnt1, uid2, vid2,
                                                         (int*)(ws + OFF_CURSOR), (int2*)(ws + OFF_ORD));

    // item transforms: q1,k1,v1,k2,self
    TArgs ti;
    ti.x = ft_item; ti.bias0 = bq1; ti.N = N_ITEM; ti.scaleOff = 0;
    ti.wtIdx[0] = 0; ti.wtIdx[1] = 1; ti.wtIdx[2] = 2; ti.wtIdx[3] = 3; ti.wtIdx[4] = 4;
    ti.out[0] = (unsigned short*)(ws + OFF_Q1);
    ti.out[1] = (unsigned short*)(ws + OFF_K1);
    ti.out[2] = (unsigned short*)(ws + OFF_V1);
    ti.out[3] = (unsigned short*)(ws + OFF_K2);
    ti.out[4] = (unsigned short*)(ws + OFF_SELF);
    transform_kernel<5><<<(N_ITEM + 63) / 64, 256, 0, stream>>>(ti, ws);

    // user transforms: q2,v2
    TArgs tu;
    tu.x = ft_user; tu.bias0 = bq2; tu.N = N_USER; tu.scaleOff = 256;
    tu.wtIdx[0] = 5; tu.wtIdx[1] = 6; tu.wtIdx[2] = 0; tu.wtIdx[3] = 0; tu.wtIdx[4] = 0;
    tu.out[0] = (unsigned short*)(ws + OFF_Q2);
    tu.out[1] = (unsigned short*)(ws + OFF_V2);
    tu.out[2] = tu.out[3] = tu.out[4] = (unsigned short*)(ws + OFF_Q2);
    transform_kernel<2><<<(N_USER + 63) / 64, 256, 0, stream>>>(tu, ws);

    // fused edge phase: one wave per dst node, register accumulation, no atomics
    edge_agg<<<(N_ITEM + 3) / 4, 256, 0, stream>>>(emb, ae1, ae2, ws);

    final_kernel<<<(N_ITEM + 63) / 64, 256, 0, stream>>>(b_agg, out, ws);
}

// Round 3
// 664.822 us; speedup vs baseline: 2.0210x; 1.2344x over previous
//
#include <hip/hip_runtime.h>
#include <hip/hip_bf16.h>

#define N_ITEM 100000
#define N_USER 50000
#define E1N 500000
#define E2N 250000
#define EALL (E1N + E2N)
#define NPAD 100352          // 98 * 1024, >= N_ITEM
#define NI_PAD 100096        // 391 * 256
#define NU_PAD 50176         // 196 * 256

// ---------------- workspace layout (bytes) ----------------
static constexpr size_t OFF_STATS = 0;        // 512 f32
static constexpr size_t OFF_SCALE = 2048;     // 512 f32
static constexpr size_t OFF_M     = 4096;     // 8 f32: per-head safe max
static constexpr size_t OFF_WPACK = 8192;     // 8 matrices, MFMA-B-fragment packed bf16 (32KB each)
static constexpr size_t SZ_WPACK  = 8ull * 32768ull;
static constexpr size_t SZ_ITEM   = (size_t)N_ITEM * 128 * 2;   // bf16
static constexpr size_t SZ_USER   = (size_t)N_USER * 128 * 2;   // bf16
static constexpr size_t OFF_Q1   = OFF_WPACK + SZ_WPACK;        // 270336
static constexpr size_t OFF_K1   = OFF_Q1 + SZ_ITEM;
static constexpr size_t OFF_V1   = OFF_K1 + SZ_ITEM;
static constexpr size_t OFF_K2   = OFF_V1 + SZ_ITEM;
static constexpr size_t OFF_SELF = OFF_K2 + SZ_ITEM;
static constexpr size_t OFF_Q2   = OFF_SELF + SZ_ITEM;
static constexpr size_t OFF_V2   = OFF_Q2 + SZ_USER;
static constexpr size_t OFF_HIST   = OFF_V2 + SZ_USER;          // NPAD ints
static constexpr size_t OFF_START  = OFF_HIST + (size_t)NPAD * 4;
static constexpr size_t OFF_CURSOR = OFF_START + (size_t)NPAD * 4;
static constexpr size_t OFF_BSUM   = OFF_CURSOR + (size_t)NPAD * 4;  // 128 ints
static constexpr size_t OFF_ORD    = OFF_BSUM + 1024;           // EALL int2, padded
static constexpr size_t OFF_AGG    = OFF_ORD + 6000128;         // f32 [N_ITEM,128]
// xb (bf16 BN'd features) aliases the agg region: xb lifetime ends before
// edge_agg writes agg (stream-ordered). XBI+XBU = 38.5MB <= 51.2MB agg.
static constexpr size_t OFF_XBI = OFF_AGG;
static constexpr size_t OFF_XBU = OFF_AGG + (size_t)NI_PAD * 256;

// ---------------- helpers ----------------
__device__ __forceinline__ float bf2f(unsigned short u) {
    return __uint_as_float(((unsigned)u) << 16);
}
__device__ __forceinline__ unsigned short f2bf(float f) {
    unsigned u = __float_as_uint(f);
    u += 0x7fffu + ((u >> 16) & 1u);   // round-to-nearest-even
    return (unsigned short)(u >> 16);
}

typedef __attribute__((ext_vector_type(8))) short bf16x8;
typedef __attribute__((ext_vector_type(4))) float f32x4;

struct P8 { const float* p[8]; };

// ---------------- pack weights into MFMA B-fragment order ----------------
// frag (m, t, kt, lane): 8 bf16 = B[k=kt*32+(lane>>4)*8+j][n=t*16+(lane&15)]
// where B[k][n] = W[n][k]. Stored contiguously: gid = ((m*8+t)*4+kt)*64+lane.
__global__ __launch_bounds__(256) void pack_w(P8 src, unsigned short* __restrict__ dst) {
    int gid = blockIdx.x * 256 + threadIdx.x;     // 0..16383
    int m = gid >> 11;
    int rem = gid & 2047;
    int t = rem >> 8;
    int kt = (rem >> 6) & 3;
    int lane = rem & 63;
    int n = t * 16 + (lane & 15);
    int k0 = kt * 32 + (lane >> 4) * 8;
    const float* wrow = src.p[m] + n * 128 + k0;
    float4 w0 = *(const float4*)(wrow);
    float4 w1 = *(const float4*)(wrow + 4);
    ushort4 o0, o1;
    o0.x = f2bf(w0.x); o0.y = f2bf(w0.y); o0.z = f2bf(w0.z); o0.w = f2bf(w0.w);
    o1.x = f2bf(w1.x); o1.y = f2bf(w1.y); o1.z = f2bf(w1.z); o1.w = f2bf(w1.w);
    *(ushort4*)(dst + (size_t)gid * 8)     = o0;
    *(ushort4*)(dst + (size_t)gid * 8 + 4) = o1;
}

// ---------------- BN stats: per-column sum/sumsq ----------------
__global__ __launch_bounds__(256) void bn_stats(const float* __restrict__ ft_item,
                                                const float* __restrict__ ft_user,
                                                float* __restrict__ stats) {
    int type = blockIdx.y;
    const float* x = type ? ft_user : ft_item;
    int N = type ? N_USER : N_ITEM;
    float* sum = stats + type * 256;
    float* sq  = sum + 128;
    int c = threadIdx.x & 127;
    int half = threadIdx.x >> 7;
    int nb = gridDim.x;
    float s = 0.f, s2 = 0.f;
    for (int r = blockIdx.x * 2 + half; r < N; r += nb * 2) {
        float v = x[r * 128 + c];
        s += v; s2 += v * v;
    }
    __shared__ float ls[256], ls2[256];
    ls[threadIdx.x] = s; ls2[threadIdx.x] = s2;
    __syncthreads();
    if (half == 0) {
        s  = ls[c]  + ls[c + 128];
        s2 = ls2[c] + ls2[c + 128];
        atomicAdd(&sum[c], s);
        atomicAdd(&sq[c], s2);
    }
}

// ---------------- BN finalize + per-head safe max ----------------
__global__ __launch_bounds__(256) void bn_finalize(const float* __restrict__ g_i, const float* __restrict__ b_i,
                                                   const float* __restrict__ g_u, const float* __restrict__ b_u,
                                                   const float* __restrict__ ae1, const float* __restrict__ ae2,
                                                   float* __restrict__ wsf) {
    int t = threadIdx.x;
    float* stats = wsf;
    float* scale = wsf + 512;           // OFF_SCALE
    float* M     = wsf + 1024;          // OFF_M
    {
        int type = t >> 7, c = t & 127;
        float N = type ? (float)N_USER : (float)N_ITEM;
        float su = stats[type * 256 + c];
        float sq = stats[type * 256 + 128 + c];
        float mu = su / N;
        float var = sq / N - mu * mu;
        float rstd = rsqrtf(var + 1e-5f);
        float g = type ? g_u[c] : g_i[c];
        float b = type ? b_u[c] : b_i[c];
        scale[type * 256 + c]       = g * rstd;
        scale[type * 256 + 128 + c] = b - mu * g * rstd;
    }
    if (t < 8) {
        float m1 = 0.f, m2 = 0.f;
        for (int j = 0; j < 16; j++) {
            m1 += fmaxf(ae1[t * 16 + j], 0.f);
            m2 += fmaxf(ae2[t * 16 + j], 0.f);
        }
        M[t] = fmaxf(m1, m2);   // uniform shift per head across both etypes
    }
}

// ---------------- BN apply + bf16 convert (padded rows -> 0) ----------------
__global__ __launch_bounds__(256) void prep_xb(const float* __restrict__ x, int N,
                                               const float* __restrict__ scaleb,
                                               unsigned short* __restrict__ xb) {
    int gid = blockIdx.x * 256 + threadIdx.x;   // one thread = 4 cols
    int r = gid >> 5, c4 = gid & 31;
    ushort4 o = make_ushort4(0, 0, 0, 0);
    if (r < N) {
        float4 v = ((const float4*)x)[(size_t)r * 32 + c4];
        float4 sc = ((const float4*)scaleb)[c4];
        float4 bi = ((const float4*)(scaleb + 128))[c4];
        o.x = f2bf(fmaf(v.x, sc.x, bi.x));
        o.y = f2bf(fmaf(v.y, sc.y, bi.y));
        o.z = f2bf(fmaf(v.z, sc.z, bi.z));
        o.w = f2bf(fmaf(v.w, sc.w, bi.w));
    }
    *(ushort4*)(xb + (size_t)gid * 4) = o;
}

// ---------------- MFMA transforms: wave = 64 rows, no LDS ----------------
struct TArgs {
    const unsigned short* xb;    // bf16 [padded,128]
    const float* bias0;          // bias for matrix 0 (q), may be null
    int N;
    int wtIdx[5];
    unsigned short* out[5];
};

template <int NMAT>
__global__ __launch_bounds__(256) void transform_mfma(TArgs args, char* __restrict__ ws) {
    const unsigned short* wpack = (const unsigned short*)(ws + OFF_WPACK);
    int tid = threadIdx.x;
    int lane = tid & 63;
    int wv = tid >> 6;
    int m15 = lane & 15, quad = lane >> 4;
    int row_base = blockIdx.x * 256 + wv * 64;

    bf16x8 a[4][4];
    #pragma unroll
    for (int rt = 0; rt < 4; rt++)
        #pragma unroll
        for (int kt = 0; kt < 4; kt++)
            a[rt][kt] = *(const bf16x8*)(args.xb + (size_t)(row_base + rt * 16 + m15) * 128 + kt * 32 + quad * 8);

    #pragma unroll
    for (int m = 0; m < NMAT; m++) {
        const unsigned short* wp = wpack + (size_t)args.wtIdx[m] * 16384;
        unsigned short* outp = args.out[m];
        #pragma unroll
        for (int t = 0; t < 8; t++) {
            bf16x8 b[4];
            #pragma unroll
            for (int kt = 0; kt < 4; kt++)
                b[kt] = *(const bf16x8*)(wp + (size_t)((t * 4 + kt) * 64 + lane) * 8);
            float bias = 0.f;
            if (m == 0 && args.bias0) bias = args.bias0[t * 16 + m15];
            #pragma unroll
            for (int rt = 0; rt < 4; rt++) {
                f32x4 acc = {bias, bias, bias, bias};
                #pragma unroll
                for (int kt = 0; kt < 4; kt++)
                    acc = __builtin_amdgcn_mfma_f32_16x16x32_bf16(a[rt][kt], b[kt], acc, 0, 0, 0);
                int r0 = row_base + rt * 16 + quad * 4;
                #pragma unroll
                for (int r = 0; r < 4; r++) {
                    int gr = r0 + r;
                    if (gr < args.N)
                        outp[(size_t)gr * 128 + t * 16 + m15] = f2bf(acc[r]);
                }
            }
        }
    }
}

// ---------------- CSR build ----------------
__global__ __launch_bounds__(256) void edge_hist(const int* __restrict__ vid1,
                                                 const int* __restrict__ vid2,
                                                 int* __restrict__ hist) {
    int e = blockIdx.x * 256 + threadIdx.x;
    if (e >= EALL) return;
    int dst = (e < E1N) ? vid1[e] : vid2[e - E1N];
    atomicAdd(&hist[dst], 1);
}

__global__ __launch_bounds__(1024) void scan_partial(const int* __restrict__ hist,
                                                     int* __restrict__ start,
                                                     int* __restrict__ bsum) {
    __shared__ int sd[1024];
    int t = threadIdx.x;
    int gid = blockIdx.x * 1024 + t;
    int v = hist[gid];
    sd[t] = v;
    __syncthreads();
    #pragma unroll
    for (int off = 1; off < 1024; off <<= 1) {
        int x = (t >= off) ? sd[t - off] : 0;
        __syncthreads();
        sd[t] += x;
        __syncthreads();
    }
    start[gid] = sd[t] - v;            // exclusive
    if (t == 1023) bsum[blockIdx.x] = sd[t];
}

__global__ __launch_bounds__(128) void scan_top(int* __restrict__ bsum) {
    __shared__ int sd[128];
    int t = threadIdx.x;
    int v = (t < 98) ? bsum[t] : 0;
    sd[t] = v;
    __syncthreads();
    #pragma unroll
    for (int off = 1; off < 128; off <<= 1) {
        int x = (t >= off) ? sd[t - off] : 0;
        __syncthreads();
        sd[t] += x;
        __syncthreads();
    }
    if (t < 98) bsum[t] = sd[t] - v;   // exclusive
}

__global__ __launch_bounds__(1024) void scan_add(int* __restrict__ start,
                                                 int* __restrict__ cursor,
                                                 const int* __restrict__ bsum) {
    int t = threadIdx.x;
    int gid = blockIdx.x * 1024 + t;
    int s = start[gid] + bsum[blockIdx.x];
    start[gid] = s;
    cursor[gid] = s;
}

__global__ __launch_bounds__(256) void edge_scatter(const int* __restrict__ uid1, const int* __restrict__ vid1,
                                                    const int* __restrict__ cnt1,
                                                    const int* __restrict__ uid2, const int* __restrict__ vid2,
                                                    int* __restrict__ cursor, int2* __restrict__ ord) {
    int e = blockIdx.x * 256 + threadIdx.x;
    if (e >= EALL) return;
    int2 rec;
    int dst;
    if (e < E1N) {
        rec.x = uid1[e]; rec.y = cnt1[e]; dst = vid1[e];
    } else {
        int ee = e - E1N;
        rec.x = uid2[ee]; rec.y = -1; dst = vid2[ee];
    }
    int pos = atomicAdd(&cursor[dst], 1);
    ord[pos] = rec;
}

// ---------------- fused edge phase: wave per dst, no atomics ----------------
__global__ __launch_bounds__(256) void edge_agg(const float* __restrict__ emb,
                                                const float* __restrict__ ae1, const float* __restrict__ ae2,
                                                char* __restrict__ ws) {
    const unsigned short* q1 = (const unsigned short*)(ws + OFF_Q1);
    const unsigned short* k1 = (const unsigned short*)(ws + OFF_K1);
    const unsigned short* v1 = (const unsigned short*)(ws + OFF_V1);
    const unsigned short* k2 = (const unsigned short*)(ws + OFF_K2);
    const unsigned short* q2 = (const unsigned short*)(ws + OFF_Q2);
    const unsigned short* v2 = (const unsigned short*)(ws + OFF_V2);
    const int* start = (const int*)(ws + OFF_START);
    const int2* ord = (const int2*)(ws + OFF_ORD);
    const float* M = (const float*)(ws + OFF_M);
    float* agg = (float*)(ws + OFF_AGG);

    int tid = threadIdx.x;
    int lane = tid & 63;
    int dst = blockIdx.x * 4 + (tid >> 6);
    if (dst >= N_ITEM) return;
    int h = lane >> 3;
    int d0 = lane << 1;

    float mh = M[h];
    float2 ae1v = *(const float2*)(ae1 + d0);
    float2 ae2v = *(const float2*)(ae2 + d0);
    unsigned k1p = *(const unsigned*)(k1 + dst * 128 + d0);
    unsigned k2p = *(const unsigned*)(k2 + dst * 128 + d0);
    float k1lo = bf2f((unsigned short)(k1p & 0xffffu)), k1hi = bf2f((unsigned short)(k1p >> 16));
    float k2lo = bf2f((unsigned short)(k2p & 0xffffu)), k2hi = bf2f((unsigned short)(k2p >> 16));

    int beg = start[dst], end = start[dst + 1];
    float acc0 = 0.f, acc1 = 0.f, s = 0.f;
    for (int i = beg; i < end; i++) {
        int2 rec = ord[i];
        bool t1 = rec.y >= 0;
        const unsigned short* qrow = (t1 ? q1 : q2) + (size_t)rec.x * 128;
        const unsigned short* vrow = (t1 ? v1 : v2) + (size_t)rec.x * 128;
        unsigned qp = *(const unsigned*)(qrow + d0);
        float x0 = bf2f((unsigned short)(qp & 0xffffu)) + (t1 ? k1lo : k2lo);
        float x1 = bf2f((unsigned short)(qp >> 16))     + (t1 ? k1hi : k2hi);
        float2 ae = t1 ? ae1v : ae2v;
        if (t1) {
            float2 ev = *(const float2*)(emb + rec.y * 128 + d0);
            x0 += ev.x; x1 += ev.y;
        }
        float t = ae.x / (1.f + __expf(-x0)) + ae.y / (1.f + __expf(-x1));
        t += __shfl_xor(t, 1);
        t += __shfl_xor(t, 2);
        t += __shfl_xor(t, 4);
        float ex = __expf(t - mh);
        s += ex;
        unsigned vp = *(const unsigned*)(vrow + d0);
        acc0 = fmaf(ex, bf2f((unsigned short)(vp & 0xffffu)), acc0);
        acc1 = fmaf(ex, bf2f((unsigned short)(vp >> 16)), acc1);
    }
    float inv = (s > 0.f) ? (1.f / s) : 0.f;
    float2 o = make_float2(acc0 * inv, acc1 * inv);
    *(float2*)(agg + (size_t)dst * 128 + d0) = o;
}

// ---------------- final: relu(agg @ Wagg.T + b + selfterm), MFMA ----------------
__global__ __launch_bounds__(256) void final_mfma(const float* __restrict__ b_agg,
                                                  float* __restrict__ out, char* __restrict__ ws) {
    const float* agg = (const float*)(ws + OFF_AGG);
    const unsigned short* selft = (const unsigned short*)(ws + OFF_SELF);
    const unsigned short* wp = (const unsigned short*)(ws + OFF_WPACK) + 7ull * 16384;
    int tid = threadIdx.x;
    int lane = tid & 63;
    int wv = tid >> 6;
    int m15 = lane & 15, quad = lane >> 4;
    int row_base = blockIdx.x * 256 + wv * 64;

    bf16x8 a[4][4];
    #pragma unroll
    for (int rt = 0; rt < 4; rt++) {
        int gr = row_base + rt * 16 + m15;
        #pragma unroll
        for (int kt = 0; kt < 4; kt++) {
            bf16x8 f = {0, 0, 0, 0, 0, 0, 0, 0};
            if (gr < N_ITEM) {
                const float* p = agg + (size_t)gr * 128 + kt * 32 + quad * 8;
                float4 v0 = *(const float4*)(p);
                float4 v1 = *(const float4*)(p + 4);
                f[0] = (short)f2bf(v0.x); f[1] = (short)f2bf(v0.y);
                f[2] = (short)f2bf(v0.z); f[3] = (short)f2bf(v0.w);
                f[4] = (short)f2bf(v1.x); f[5] = (short)f2bf(v1.y);
                f[6] = (short)f2bf(v1.z); f[7] = (short)f2bf(v1.w);
            }
            a[rt][kt] = f;
        }
    }

    #pragma unroll
    for (int t = 0; t < 8; t++) {
        bf16x8 b[4];
        #pragma unroll
        for (int kt = 0; kt < 4; kt++)
            b[kt] = *(const bf16x8*)(wp + (size_t)((t * 4 + kt) * 64 + lane) * 8);
        float bias = b_agg[t * 16 + m15];
        #pragma unroll
        for (int rt = 0; rt < 4; rt++) {
            f32x4 acc = {bias, bias, bias, bias};
            #pragma unroll
            for (int kt = 0; kt < 4; kt++)
                acc = __builtin_amdgcn_mfma_f32_16x16x32_bf16(a[rt][kt], b[kt], acc, 0, 0, 0);
            int r0 = row_base + rt * 16 + quad * 4;
            #pragma unroll
            for (int r = 0; r < 4; r++) {
                int gr = r0 + r;
                if (gr < N_ITEM) {
                    size_t idx = (size_t)gr * 128 + t * 16 + m15;
                    float sv = bf2f(selft[idx]);
                    out[idx] = fmaxf(acc[r] + sv, 0.f);
                }
            }
        }
    }
}

// ---------------- host ----------------
extern "C" void kernel_launch(void* const* d_in, const int* in_sizes, int n_in,
                              void* d_out, int out_size, void* d_ws, size_t ws_size,
                              hipStream_t stream) {
    char* ws = (char*)d_ws;

    const float* ft_item = (const float*)d_in[0];
    const float* ft_user = (const float*)d_in[1];
    const float* bng_i = (const float*)d_in[2];
    const float* bnb_i = (const float*)d_in[3];
    const float* bng_u = (const float*)d_in[4];
    const float* bnb_u = (const float*)d_in[5];
    const float* Wq1 = (const float*)d_in[6];
    const float* bq1 = (const float*)d_in[7];
    const float* Wk1 = (const float*)d_in[8];
    const float* Wv1 = (const float*)d_in[9];
    const float* ae1 = (const float*)d_in[10];
    const float* emb = (const float*)d_in[11];
    const float* Wq2 = (const float*)d_in[12];
    const float* bq2 = (const float*)d_in[13];
    const float* Wk2 = (const float*)d_in[14];
    const float* Wv2 = (const float*)d_in[15];
    const float* ae2 = (const float*)d_in[16];
    const float* W_agg = (const float*)d_in[17];
    const float* b_agg = (const float*)d_in[18];
    const float* W_self = (const float*)d_in[19];
    const int* uid1 = (const int*)d_in[20];
    const int* vid1 = (const int*)d_in[21];
    const int* cnt1 = (const int*)d_in[22];
    const int* uid2 = (const int*)d_in[23];
    const int* vid2 = (const int*)d_in[24];
    float* out = (float*)d_out;

    hipMemsetAsync(ws + OFF_STATS, 0, 2048, stream);
    hipMemsetAsync(ws + OFF_HIST, 0, (size_t)NPAD * 4, stream);

    // pack weights: order q1,k1,v1,k2,self,q2,v2,agg
    P8 p8;
    p8.p[0] = Wq1; p8.p[1] = Wk1; p8.p[2] = Wv1; p8.p[3] = Wk2;
    p8.p[4] = W_self; p8.p[5] = Wq2; p8.p[6] = Wv2; p8.p[7] = W_agg;
    pack_w<<<64, 256, 0, stream>>>(p8, (unsigned short*)(ws + OFF_WPACK));

    bn_stats<<<dim3(256, 2), 256, 0, stream>>>(ft_item, ft_user, (float*)(ws + OFF_STATS));
    bn_finalize<<<1, 256, 0, stream>>>(bng_i, bnb_i, bng_u, bnb_u, ae1, ae2, (float*)ws);

    // CSR build
    edge_hist<<<(EALL + 255) / 256, 256, 0, stream>>>(vid1, vid2, (int*)(ws + OFF_HIST));
    scan_partial<<<98, 1024, 0, stream>>>((int*)(ws + OFF_HIST), (int*)(ws + OFF_START), (int*)(ws + OFF_BSUM));
    scan_top<<<1, 128, 0, stream>>>((int*)(ws + OFF_BSUM));
    scan_add<<<98, 1024, 0, stream>>>((int*)(ws + OFF_START), (int*)(ws + OFF_CURSOR), (int*)(ws + OFF_BSUM));
    edge_scatter<<<(EALL + 255) / 256, 256, 0, stream>>>(uid1, vid1, cnt1, uid2, vid2,
                                                         (int*)(ws + OFF_CURSOR), (int2*)(ws + OFF_ORD));

    // BN apply + bf16 convert (xb aliases agg region; used only before edge_agg)
    prep_xb<<<NI_PAD * 32 / 256, 256, 0, stream>>>(ft_item, N_ITEM, (float*)(ws + OFF_SCALE),
                                                   (unsigned short*)(ws + OFF_XBI));
    prep_xb<<<NU_PAD * 32 / 256, 256, 0, stream>>>(ft_user, N_USER, (float*)(ws + OFF_SCALE) + 256,
                                                   (unsigned short*)(ws + OFF_XBU));

    // item transforms: q1,k1,v1,k2,self (MFMA)
    TArgs ti;
    ti.xb = (const unsigned short*)(ws + OFF_XBI);
    ti.bias0 = bq1; ti.N = N_ITEM;
    ti.wtIdx[0] = 0; ti.wtIdx[1] = 1; ti.wtIdx[2] = 2; ti.wtIdx[3] = 3; ti.wtIdx[4] = 4;
    ti.out[0] = (unsigned short*)(ws + OFF_Q1);
    ti.out[1] = (unsigned short*)(ws + OFF_K1);
    ti.out[2] = (unsigned short*)(ws + OFF_V1);
    ti.out[3] = (unsigned short*)(ws + OFF_K2);
    ti.out[4] = (unsigned short*)(ws + OFF_SELF);
    transform_mfma<5><<<NI_PAD / 256, 256, 0, stream>>>(ti, ws);

    // user transforms: q2,v2 (MFMA)
    TArgs tu;
    tu.xb = (const unsigned short*)(ws + OFF_XBU);
    tu.bias0 = bq2; tu.N = N_USER;
    tu.wtIdx[0] = 5; tu.wtIdx[1] = 6; tu.wtIdx[2] = 0; tu.wtIdx[3] = 0; tu.wtIdx[4] = 0;
    tu.out[0] = (unsigned short*)(ws + OFF_Q2);
    tu.out[1] = (unsigned short*)(ws + OFF_V2);
    tu.out[2] = tu.out[3] = tu.out[4] = (unsigned short*)(ws + OFF_Q2);
    transform_mfma<2><<<NU_PAD / 256, 256, 0, stream>>>(tu, ws);

    // fused edge phase: one wave per dst node, register accumulation, no atomics
    edge_agg<<<(N_ITEM + 3) / 4, 256, 0, stream>>>(emb, ae1, ae2, ws);

    final_mfma<<<NI_PAD / 256, 256, 0, stream>>>(b_agg, out, ws);
}

// Round 4
// 555.471 us; speedup vs baseline: 2.4188x; 1.1969x over previous
//
#include <hip/hip_runtime.h>
#include <hip/hip_bf16.h>

#define N_ITEM 100000
#define N_USER 50000
#define N_ALL  150000
#define E1N 500000
#define E2N 250000
#define EALL (E1N + E2N)
#define NPAD 100352          // 98 * 1024, >= N_ITEM
#define NI_PAD 100096        // 782 * 128
#define NU_PAD 50176         // 392 * 128

// ---------------- workspace layout (bytes) ----------------
static constexpr size_t OFF_STATS = 0;        // 512 f32
static constexpr size_t OFF_SCALE = 2048;     // 512 f32
static constexpr size_t OFF_M     = 4096;     // 8 f32: per-head safe max
static constexpr size_t OFF_WPACK = 8192;     // 8 matrices, MFMA-B packed bf16
static constexpr size_t SZ_WPACK  = 8ull * 32768ull;
static constexpr size_t SZ_ITEM   = (size_t)N_ITEM * 128 * 2;   // bf16
static constexpr size_t SZ_CAT    = (size_t)N_ALL * 128 * 2;    // bf16, item rows then user rows
static constexpr size_t OFF_QC   = OFF_WPACK + SZ_WPACK;        // q1 rows 0..N_ITEM-1, q2 rows N_ITEM..
static constexpr size_t OFF_VC   = OFF_QC + SZ_CAT;             // v1 then v2
static constexpr size_t OFF_K1   = OFF_VC + SZ_CAT;
static constexpr size_t OFF_K2   = OFF_K1 + SZ_ITEM;
static constexpr size_t OFF_SELF = OFF_K2 + SZ_ITEM;
static constexpr size_t OFF_HIST   = OFF_SELF + SZ_ITEM;        // NPAD ints
static constexpr size_t OFF_START  = OFF_HIST + (size_t)NPAD * 4;
static constexpr size_t OFF_CURSOR = OFF_START + (size_t)NPAD * 4;
static constexpr size_t OFF_BSUM   = OFF_CURSOR + (size_t)NPAD * 4;  // 128 ints
static constexpr size_t OFF_ORD    = OFF_BSUM + 1024;           // EALL int2
static constexpr size_t OFF_AGG    = OFF_ORD + 6000128;         // f32 [N_ITEM,128]

// ---------------- helpers ----------------
__device__ __forceinline__ float bf2f(unsigned short u) {
    return __uint_as_float(((unsigned)u) << 16);
}
__device__ __forceinline__ unsigned short f2bf(float f) {
    unsigned u = __float_as_uint(f);
    u += 0x7fffu + ((u >> 16) & 1u);   // round-to-nearest-even
    return (unsigned short)(u >> 16);
}

typedef __attribute__((ext_vector_type(8))) short bf16x8;
typedef __attribute__((ext_vector_type(4))) float f32x4;

struct P8 { const float* p[8]; };

// ---------------- pack weights into MFMA B-fragment order ----------------
// frag (m, t, kt, lane): 8 bf16 = B[k=kt*32+(lane>>4)*8+j][n=t*16+(lane&15)]
// where B[k][n] = W[n][k]. gid = ((m*8+t)*4+kt)*64+lane.
__global__ __launch_bounds__(256) void pack_w(P8 src, unsigned short* __restrict__ dst) {
    int gid = blockIdx.x * 256 + threadIdx.x;     // 0..16383
    int m = gid >> 11;
    int rem = gid & 2047;
    int t = rem >> 8;
    int kt = (rem >> 6) & 3;
    int lane = rem & 63;
    int n = t * 16 + (lane & 15);
    int k0 = kt * 32 + (lane >> 4) * 8;
    const float* wrow = src.p[m] + n * 128 + k0;
    float4 w0 = *(const float4*)(wrow);
    float4 w1 = *(const float4*)(wrow + 4);
    ushort4 o0, o1;
    o0.x = f2bf(w0.x); o0.y = f2bf(w0.y); o0.z = f2bf(w0.z); o0.w = f2bf(w0.w);
    o1.x = f2bf(w1.x); o1.y = f2bf(w1.y); o1.z = f2bf(w1.z); o1.w = f2bf(w1.w);
    *(ushort4*)(dst + (size_t)gid * 8)     = o0;
    *(ushort4*)(dst + (size_t)gid * 8 + 4) = o1;
}

// ---------------- BN stats ----------------
__global__ __launch_bounds__(256) void bn_stats(const float* __restrict__ ft_item,
                                                const float* __restrict__ ft_user,
                                                float* __restrict__ stats) {
    int type = blockIdx.y;
    const float* x = type ? ft_user : ft_item;
    int N = type ? N_USER : N_ITEM;
    float* sum = stats + type * 256;
    float* sq  = sum + 128;
    int c = threadIdx.x & 127;
    int half = threadIdx.x >> 7;
    int nb = gridDim.x;
    float s = 0.f, s2 = 0.f;
    for (int r = blockIdx.x * 2 + half; r < N; r += nb * 2) {
        float v = x[r * 128 + c];
        s += v; s2 += v * v;
    }
    __shared__ float ls[256], ls2[256];
    ls[threadIdx.x] = s; ls2[threadIdx.x] = s2;
    __syncthreads();
    if (half == 0) {
        s  = ls[c]  + ls[c + 128];
        s2 = ls2[c] + ls2[c + 128];
        atomicAdd(&sum[c], s);
        atomicAdd(&sq[c], s2);
    }
}

// ---------------- BN finalize + per-head safe max ----------------
__global__ __launch_bounds__(256) void bn_finalize(const float* __restrict__ g_i, const float* __restrict__ b_i,
                                                   const float* __restrict__ g_u, const float* __restrict__ b_u,
                                                   const float* __restrict__ ae1, const float* __restrict__ ae2,
                                                   float* __restrict__ wsf) {
    int t = threadIdx.x;
    float* stats = wsf;
    float* scale = wsf + 512;           // OFF_SCALE
    float* M     = wsf + 1024;          // OFF_M
    {
        int type = t >> 7, c = t & 127;
        float N = type ? (float)N_USER : (float)N_ITEM;
        float su = stats[type * 256 + c];
        float sq = stats[type * 256 + 128 + c];
        float mu = su / N;
        float var = sq / N - mu * mu;
        float rstd = rsqrtf(var + 1e-5f);
        float g = type ? g_u[c] : g_i[c];
        float b = type ? b_u[c] : b_i[c];
        scale[type * 256 + c]       = g * rstd;
        scale[type * 256 + 128 + c] = b - mu * g * rstd;
    }
    if (t < 8) {
        float m1 = 0.f, m2 = 0.f;
        for (int j = 0; j < 16; j++) {
            m1 += fmaxf(ae1[t * 16 + j], 0.f);
            m2 += fmaxf(ae2[t * 16 + j], 0.f);
        }
        M[t] = fmaxf(m1, m2);   // uniform shift per head across both etypes
    }
}

// ---------------- MFMA transforms: BN fused, LDS-staged coalesced stores ----
struct TArgs {
    const float* x;              // raw f32 features
    const float* bias0;          // bias for matrix 0 (q), may be null
    int N;
    int scaleOff;                // 0 item, 256 user
    int wtIdx[5];
    unsigned short* out[5];
};

#define TPITCH 136   // bf16 row pitch in LDS (272B: 16B-aligned rows, ~2-way write conflicts)

template <int NMAT>
__global__ __launch_bounds__(128) void transform_mfma(TArgs args, char* __restrict__ ws) {
    __shared__ unsigned short stg[2][64 * TPITCH];
    const unsigned short* wpack = (const unsigned short*)(ws + OFF_WPACK);
    const float* scaleb = (const float*)(ws + OFF_SCALE) + args.scaleOff;
    int tid = threadIdx.x, lane = tid & 63, wv = tid >> 6;
    int m15 = lane & 15, quad = lane >> 4;
    int row_base = blockIdx.x * 128 + wv * 64;
    unsigned short* my = stg[wv];

    // A-fragments with inline BN (f32 -> bf16)
    bf16x8 a[4][4];
    #pragma unroll
    for (int kt = 0; kt < 4; kt++) {
        int c0 = kt * 32 + quad * 8;
        float4 sc0 = *(const float4*)(scaleb + c0);
        float4 sc1 = *(const float4*)(scaleb + c0 + 4);
        float4 bi0 = *(const float4*)(scaleb + 128 + c0);
        float4 bi1 = *(const float4*)(scaleb + 128 + c0 + 4);
        #pragma unroll
        for (int rt = 0; rt < 4; rt++) {
            int gr = row_base + rt * 16 + m15;
            bf16x8 f = {0, 0, 0, 0, 0, 0, 0, 0};
            if (gr < args.N) {
                const float* p = args.x + (size_t)gr * 128 + c0;
                float4 v0 = *(const float4*)p;
                float4 v1 = *(const float4*)(p + 4);
                f[0] = (short)f2bf(fmaf(v0.x, sc0.x, bi0.x));
                f[1] = (short)f2bf(fmaf(v0.y, sc0.y, bi0.y));
                f[2] = (short)f2bf(fmaf(v0.z, sc0.z, bi0.z));
                f[3] = (short)f2bf(fmaf(v0.w, sc0.w, bi0.w));
                f[4] = (short)f2bf(fmaf(v1.x, sc1.x, bi1.x));
                f[5] = (short)f2bf(fmaf(v1.y, sc1.y, bi1.y));
                f[6] = (short)f2bf(fmaf(v1.z, sc1.z, bi1.z));
                f[7] = (short)f2bf(fmaf(v1.w, sc1.w, bi1.w));
            }
            a[rt][kt] = f;
        }
    }

    #pragma unroll
    for (int m = 0; m < NMAT; m++) {
        const unsigned short* wp = wpack + (size_t)args.wtIdx[m] * 16384;
        #pragma unroll
        for (int t = 0; t < 8; t++) {
            bf16x8 b[4];
            #pragma unroll
            for (int kt = 0; kt < 4; kt++)
                b[kt] = *(const bf16x8*)(wp + (size_t)((t * 4 + kt) * 64 + lane) * 8);
            float bias = 0.f;
            if (m == 0 && args.bias0) bias = args.bias0[t * 16 + m15];
            #pragma unroll
            for (int rt = 0; rt < 4; rt++) {
                f32x4 acc = {bias, bias, bias, bias};
                #pragma unroll
                for (int kt = 0; kt < 4; kt++)
                    acc = __builtin_amdgcn_mfma_f32_16x16x32_bf16(a[rt][kt], b[kt], acc, 0, 0, 0);
                #pragma unroll
                for (int r = 0; r < 4; r++)
                    my[(rt * 16 + quad * 4 + r) * TPITCH + t * 16 + m15] = f2bf(acc[r]);
            }
        }
        __syncthreads();
        unsigned short* outp = args.out[m];
        #pragma unroll
        for (int i = 0; i < 16; i++) {
            int chunk = i * 64 + lane;         // 1024 chunks of 8 bf16
            int row = chunk >> 4;
            int c8 = (chunk & 15) * 8;
            if (row_base + row < args.N) {
                bf16x8 v = *(const bf16x8*)(my + row * TPITCH + c8);
                *(bf16x8*)(outp + (size_t)(row_base + row) * 128 + c8) = v;
            }
        }
        __syncthreads();
    }
}

// ---------------- CSR build ----------------
__global__ __launch_bounds__(256) void edge_hist(const int* __restrict__ vid1,
                                                 const int* __restrict__ vid2,
                                                 int* __restrict__ hist) {
    int e = blockIdx.x * 256 + threadIdx.x;
    if (e >= EALL) return;
    int dst = (e < E1N) ? vid1[e] : vid2[e - E1N];
    atomicAdd(&hist[dst], 1);
}

__global__ __launch_bounds__(1024) void scan_partial(const int* __restrict__ hist,
                                                     int* __restrict__ start,
                                                     int* __restrict__ bsum) {
    __shared__ int sd[1024];
    int t = threadIdx.x;
    int gid = blockIdx.x * 1024 + t;
    int v = hist[gid];
    sd[t] = v;
    __syncthreads();
    #pragma unroll
    for (int off = 1; off < 1024; off <<= 1) {
        int x = (t >= off) ? sd[t - off] : 0;
        __syncthreads();
        sd[t] += x;
        __syncthreads();
    }
    start[gid] = sd[t] - v;            // exclusive
    if (t == 1023) bsum[blockIdx.x] = sd[t];
}

__global__ __launch_bounds__(128) void scan_top(int* __restrict__ bsum) {
    __shared__ int sd[128];
    int t = threadIdx.x;
    int v = (t < 98) ? bsum[t] : 0;
    sd[t] = v;
    __syncthreads();
    #pragma unroll
    for (int off = 1; off < 128; off <<= 1) {
        int x = (t >= off) ? sd[t - off] : 0;
        __syncthreads();
        sd[t] += x;
        __syncthreads();
    }
    if (t < 98) bsum[t] = sd[t] - v;   // exclusive
}

__global__ __launch_bounds__(1024) void scan_add(int* __restrict__ start,
                                                 int* __restrict__ cursor,
                                                 const int* __restrict__ bsum) {
    int t = threadIdx.x;
    int gid = blockIdx.x * 1024 + t;
    int s = start[gid] + bsum[blockIdx.x];
    start[gid] = s;
    cursor[gid] = s;
}

// scatter: {unified src row (item rows, then user rows offset by N_ITEM), cnt|-1}
__global__ __launch_bounds__(256) void edge_scatter(const int* __restrict__ uid1, const int* __restrict__ vid1,
                                                    const int* __restrict__ cnt1,
                                                    const int* __restrict__ uid2, const int* __restrict__ vid2,
                                                    int* __restrict__ cursor, int2* __restrict__ ord) {
    int e = blockIdx.x * 256 + threadIdx.x;
    if (e >= EALL) return;
    int2 rec;
    int dst;
    if (e < E1N) {
        rec.x = uid1[e]; rec.y = cnt1[e]; dst = vid1[e];
    } else {
        int ee = e - E1N;
        rec.x = N_ITEM + uid2[ee]; rec.y = -1; dst = vid2[ee];
    }
    int pos = atomicAdd(&cursor[dst], 1);
    ord[pos] = rec;
}

// ---------------- fused edge phase: wave per dst, 2 edges per iter ----------
__global__ __launch_bounds__(256) void edge_agg(const float* __restrict__ emb,
                                                const float* __restrict__ ae1, const float* __restrict__ ae2,
                                                char* __restrict__ ws) {
    const unsigned short* qc = (const unsigned short*)(ws + OFF_QC);
    const unsigned short* vc = (const unsigned short*)(ws + OFF_VC);
    const unsigned short* k1 = (const unsigned short*)(ws + OFF_K1);
    const unsigned short* k2 = (const unsigned short*)(ws + OFF_K2);
    const int* start = (const int*)(ws + OFF_START);
    const int2* ord = (const int2*)(ws + OFF_ORD);
    const float* M = (const float*)(ws + OFF_M);
    float* agg = (float*)(ws + OFF_AGG);

    int tid = threadIdx.x;
    int lane = tid & 63;
    int half = lane >> 5;     // which edge of the pair
    int l = lane & 31;
    int d0 = l << 2;          // 4 dims per lane
    int h = l >> 2;           // head
    int dst = blockIdx.x * 4 + (tid >> 6);
    if (dst >= N_ITEM) return;

    float mh = M[h];
    float4 ae1v = *(const float4*)(ae1 + d0);
    float4 ae2v = *(const float4*)(ae2 + d0);
    ushort4 k1p = *(const ushort4*)(k1 + (size_t)dst * 128 + d0);
    ushort4 k2p = *(const ushort4*)(k2 + (size_t)dst * 128 + d0);
    float4 k1v = make_float4(bf2f(k1p.x), bf2f(k1p.y), bf2f(k1p.z), bf2f(k1p.w));
    float4 k2v = make_float4(bf2f(k2p.x), bf2f(k2p.y), bf2f(k2p.z), bf2f(k2p.w));

    int beg = start[dst], end = start[dst + 1];
    float a0 = 0.f, a1 = 0.f, a2 = 0.f, a3 = 0.f, s = 0.f;
    for (int i = beg + half; i < end; i += 2) {
        int2 rec = ord[i];
        bool t1 = rec.y >= 0;
        ushort4 qp = *(const ushort4*)(qc + (size_t)rec.x * 128 + d0);
        float x0 = bf2f(qp.x) + (t1 ? k1v.x : k2v.x);
        float x1 = bf2f(qp.y) + (t1 ? k1v.y : k2v.y);
        float x2 = bf2f(qp.z) + (t1 ? k1v.z : k2v.z);
        float x3 = bf2f(qp.w) + (t1 ? k1v.w : k2v.w);
        if (t1) {
            float4 ev = *(const float4*)(emb + (size_t)rec.y * 128 + d0);
            x0 += ev.x; x1 += ev.y; x2 += ev.z; x3 += ev.w;
        }
        float4 ae = t1 ? ae1v : ae2v;
        float t = ae.x * __builtin_amdgcn_rcpf(1.f + __expf(-x0))
                + ae.y * __builtin_amdgcn_rcpf(1.f + __expf(-x1))
                + ae.z * __builtin_amdgcn_rcpf(1.f + __expf(-x2))
                + ae.w * __builtin_amdgcn_rcpf(1.f + __expf(-x3));
        t += __shfl_xor(t, 1);
        t += __shfl_xor(t, 2);
        float ex = __expf(t - mh);
        s += ex;
        ushort4 vp = *(const ushort4*)(vc + (size_t)rec.x * 128 + d0);
        a0 = fmaf(ex, bf2f(vp.x), a0);
        a1 = fmaf(ex, bf2f(vp.y), a1);
        a2 = fmaf(ex, bf2f(vp.z), a2);
        a3 = fmaf(ex, bf2f(vp.w), a3);
    }
    // combine the two half-wave edge streams
    s  += __shfl_xor(s, 32);
    a0 += __shfl_xor(a0, 32);
    a1 += __shfl_xor(a1, 32);
    a2 += __shfl_xor(a2, 32);
    a3 += __shfl_xor(a3, 32);
    if (half == 0) {
        float inv = (s > 0.f) ? (1.f / s) : 0.f;
        float4 o = make_float4(a0 * inv, a1 * inv, a2 * inv, a3 * inv);
        *(float4*)(agg + (size_t)dst * 128 + d0) = o;
    }
}

// ---------------- final: relu(agg @ Wagg.T + b + selfterm), LDS-staged ------
#define FPITCH 132   // f32 row pitch in LDS (528B, 16B-aligned; 2-way write conflicts)

__global__ __launch_bounds__(64) void final_mfma(const float* __restrict__ b_agg,
                                                 float* __restrict__ out, char* __restrict__ ws) {
    __shared__ float stg[64 * FPITCH];
    const float* agg = (const float*)(ws + OFF_AGG);
    const unsigned short* selft = (const unsigned short*)(ws + OFF_SELF);
    const unsigned short* wp = (const unsigned short*)(ws + OFF_WPACK) + 7ull * 16384;
    int lane = threadIdx.x & 63;
    int m15 = lane & 15, quad = lane >> 4;
    int row_base = blockIdx.x * 64;

    bf16x8 a[4][4];
    #pragma unroll
    for (int rt = 0; rt < 4; rt++) {
        int gr = row_base + rt * 16 + m15;
        #pragma unroll
        for (int kt = 0; kt < 4; kt++) {
            bf16x8 f = {0, 0, 0, 0, 0, 0, 0, 0};
            if (gr < N_ITEM) {
                const float* p = agg + (size_t)gr * 128 + kt * 32 + quad * 8;
                float4 v0 = *(const float4*)(p);
                float4 v1 = *(const float4*)(p + 4);
                f[0] = (short)f2bf(v0.x); f[1] = (short)f2bf(v0.y);
                f[2] = (short)f2bf(v0.z); f[3] = (short)f2bf(v0.w);
                f[4] = (short)f2bf(v1.x); f[5] = (short)f2bf(v1.y);
                f[6] = (short)f2bf(v1.z); f[7] = (short)f2bf(v1.w);
            }
            a[rt][kt] = f;
        }
    }

    #pragma unroll
    for (int t = 0; t < 8; t++) {
        bf16x8 b[4];
        #pragma unroll
        for (int kt = 0; kt < 4; kt++)
            b[kt] = *(const bf16x8*)(wp + (size_t)((t * 4 + kt) * 64 + lane) * 8);
        float bias = b_agg[t * 16 + m15];
        #pragma unroll
        for (int rt = 0; rt < 4; rt++) {
            f32x4 acc = {bias, bias, bias, bias};
            #pragma unroll
            for (int kt = 0; kt < 4; kt++)
                acc = __builtin_amdgcn_mfma_f32_16x16x32_bf16(a[rt][kt], b[kt], acc, 0, 0, 0);
            #pragma unroll
            for (int r = 0; r < 4; r++)
                stg[(rt * 16 + quad * 4 + r) * FPITCH + t * 16 + m15] = acc[r];
        }
    }
    __syncthreads();
    #pragma unroll
    for (int i = 0; i < 32; i++) {
        int chunk = i * 64 + lane;       // 2048 chunks of 4 f32
        int row = chunk >> 5;
        int c4 = (chunk & 31) * 4;
        int gr = row_base + row;
        if (gr < N_ITEM) {
            float4 v = *(const float4*)(stg + row * FPITCH + c4);
            ushort4 st = *(const ushort4*)(selft + (size_t)gr * 128 + c4);
            float4 o;
            o.x = fmaxf(v.x + bf2f(st.x), 0.f);
            o.y = fmaxf(v.y + bf2f(st.y), 0.f);
            o.z = fmaxf(v.z + bf2f(st.z), 0.f);
            o.w = fmaxf(v.w + bf2f(st.w), 0.f);
            *(float4*)(out + (size_t)gr * 128 + c4) = o;
        }
    }
}

// ---------------- host ----------------
extern "C" void kernel_launch(void* const* d_in, const int* in_sizes, int n_in,
                              void* d_out, int out_size, void* d_ws, size_t ws_size,
                              hipStream_t stream) {
    char* ws = (char*)d_ws;

    const float* ft_item = (const float*)d_in[0];
    const float* ft_user = (const float*)d_in[1];
    const float* bng_i = (const float*)d_in[2];
    const float* bnb_i = (const float*)d_in[3];
    const float* bng_u = (const float*)d_in[4];
    const float* bnb_u = (const float*)d_in[5];
    const float* Wq1 = (const float*)d_in[6];
    const float* bq1 = (const float*)d_in[7];
    const float* Wk1 = (const float*)d_in[8];
    const float* Wv1 = (const float*)d_in[9];
    const float* ae1 = (const float*)d_in[10];
    const float* emb = (const float*)d_in[11];
    const float* Wq2 = (const float*)d_in[12];
    const float* bq2 = (const float*)d_in[13];
    const float* Wk2 = (const float*)d_in[14];
    const float* Wv2 = (const float*)d_in[15];
    const float* ae2 = (const float*)d_in[16];
    const float* W_agg = (const float*)d_in[17];
    const float* b_agg = (const float*)d_in[18];
    const float* W_self = (const float*)d_in[19];
    const int* uid1 = (const int*)d_in[20];
    const int* vid1 = (const int*)d_in[21];
    const int* cnt1 = (const int*)d_in[22];
    const int* uid2 = (const int*)d_in[23];
    const int* vid2 = (const int*)d_in[24];
    float* out = (float*)d_out;

    hipMemsetAsync(ws + OFF_STATS, 0, 2048, stream);
    hipMemsetAsync(ws + OFF_HIST, 0, (size_t)NPAD * 4, stream);

    // pack weights: order q1,k1,v1,k2,self,q2,v2,agg
    P8 p8;
    p8.p[0] = Wq1; p8.p[1] = Wk1; p8.p[2] = Wv1; p8.p[3] = Wk2;
    p8.p[4] = W_self; p8.p[5] = Wq2; p8.p[6] = Wv2; p8.p[7] = W_agg;
    pack_w<<<64, 256, 0, stream>>>(p8, (unsigned short*)(ws + OFF_WPACK));

    bn_stats<<<dim3(256, 2), 256, 0, stream>>>(ft_item, ft_user, (float*)(ws + OFF_STATS));
    bn_finalize<<<1, 256, 0, stream>>>(bng_i, bnb_i, bng_u, bnb_u, ae1, ae2, (float*)ws);

    // CSR build
    edge_hist<<<(EALL + 255) / 256, 256, 0, stream>>>(vid1, vid2, (int*)(ws + OFF_HIST));
    scan_partial<<<98, 1024, 0, stream>>>((int*)(ws + OFF_HIST), (int*)(ws + OFF_START), (int*)(ws + OFF_BSUM));
    scan_top<<<1, 128, 0, stream>>>((int*)(ws + OFF_BSUM));
    scan_add<<<98, 1024, 0, stream>>>((int*)(ws + OFF_START), (int*)(ws + OFF_CURSOR), (int*)(ws + OFF_BSUM));
    edge_scatter<<<(EALL + 255) / 256, 256, 0, stream>>>(uid1, vid1, cnt1, uid2, vid2,
                                                         (int*)(ws + OFF_CURSOR), (int2*)(ws + OFF_ORD));

    unsigned short* QC = (unsigned short*)(ws + OFF_QC);
    unsigned short* VC = (unsigned short*)(ws + OFF_VC);

    // item transforms: q1,k1,v1,k2,self (MFMA, BN fused)
    TArgs ti;
    ti.x = ft_item; ti.bias0 = bq1; ti.N = N_ITEM; ti.scaleOff = 0;
    ti.wtIdx[0] = 0; ti.wtIdx[1] = 1; ti.wtIdx[2] = 2; ti.wtIdx[3] = 3; ti.wtIdx[4] = 4;
    ti.out[0] = QC;
    ti.out[1] = (unsigned short*)(ws + OFF_K1);
    ti.out[2] = VC;
    ti.out[3] = (unsigned short*)(ws + OFF_K2);
    ti.out[4] = (unsigned short*)(ws + OFF_SELF);
    transform_mfma<5><<<NI_PAD / 128, 128, 0, stream>>>(ti, ws);

    // user transforms: q2,v2 -> concatenated after item rows
    TArgs tu;
    tu.x = ft_user; tu.bias0 = bq2; tu.N = N_USER; tu.scaleOff = 256;
    tu.wtIdx[0] = 5; tu.wtIdx[1] = 6; tu.wtIdx[2] = 0; tu.wtIdx[3] = 0; tu.wtIdx[4] = 0;
    tu.out[0] = QC + (size_t)N_ITEM * 128;
    tu.out[1] = VC + (size_t)N_ITEM * 128;
    tu.out[2] = tu.out[3] = tu.out[4] = tu.out[0];
    transform_mfma<2><<<NU_PAD / 128, 128, 0, stream>>>(tu, ws);

    // fused edge phase: wave per dst, two edges in flight, no atomics
    edge_agg<<<(N_ITEM + 3) / 4, 256, 0, stream>>>(emb, ae1, ae2, ws);

    final_mfma<<<NI_PAD / 64, 64, 0, stream>>>(b_agg, out, ws);
}

// Round 5
// 549.080 us; speedup vs baseline: 2.4470x; 1.0116x over previous
//
#include <hip/hip_runtime.h>
#include <hip/hip_bf16.h>

#define N_ITEM 100000
#define N_USER 50000
#define N_ALL  150000
#define E1N 500000
#define E2N 250000
#define EALL (E1N + E2N)
#define NPAD 100352          // 98 * 1024, >= N_ITEM+1
#define NI_PAD 100096        // 391 * 256
#define NU_PAD 50176         // 196 * 256

// ---------------- workspace layout (bytes) ----------------
static constexpr size_t OFF_STATS = 0;                       // 512 f32 (zeroed)
static constexpr size_t OFF_HIST  = 2048;                    // NPAD ints (zeroed, adjacent -> one memset)
static constexpr size_t OFF_SCALE = OFF_HIST + (size_t)NPAD * 4;       // 512 f32
static constexpr size_t OFF_M     = OFF_SCALE + 2048;                  // 8 f32
static constexpr size_t OFF_WPACK = 409600;                  // 8 matrices bf16 frag-packed
static constexpr size_t OFF_QC    = OFF_WPACK + 8ull * 32768ull;       // bf16 [N_ALL,128] q1|q2
static constexpr size_t OFF_VC    = OFF_QC + (size_t)N_ALL * 256;      // bf16 v1|v2
static constexpr size_t OFF_K1    = OFF_VC + (size_t)N_ALL * 256;
static constexpr size_t OFF_K2    = OFF_K1 + (size_t)N_ITEM * 256;
static constexpr size_t OFF_SELF  = OFF_K2 + (size_t)N_ITEM * 256;
static constexpr size_t OFF_START = OFF_SELF + (size_t)N_ITEM * 256;   // NPAD ints (within-chunk exclusive)
static constexpr size_t OFF_CURSOR= OFF_START + (size_t)NPAD * 4;      // NPAD ints
static constexpr size_t OFF_BSUM  = OFF_CURSOR + (size_t)NPAD * 4;     // 128 ints
static constexpr size_t OFF_ORD   = OFF_BSUM + 1024;                   // EALL int2
static constexpr size_t OFF_AGG   = OFF_ORD + (size_t)EALL * 8 + 128;  // f32 [N_ITEM,128]

// ---------------- helpers ----------------
__device__ __forceinline__ float bf2f(unsigned short u) {
    return __uint_as_float(((unsigned)u) << 16);
}
__device__ __forceinline__ unsigned short f2bf(float f) {
    unsigned u = __float_as_uint(f);
    u += 0x7fffu + ((u >> 16) & 1u);   // round-to-nearest-even
    return (unsigned short)(u >> 16);
}

typedef __attribute__((ext_vector_type(8))) short bf16x8;
typedef __attribute__((ext_vector_type(4))) float f32x4;

// ---------------- prologue: pack_w + bn_stats + edge_hist in one grid ------
struct ProArgs {
    const float* w[8];
    const float* ft_item;
    const float* ft_user;
    const int* vid1;
    const int* vid2;
};
#define PRO_PACK 64
#define PRO_STAT 512
#define PRO_HIST 2930   // ceil(EALL/256)

__global__ __launch_bounds__(256) void prologue(ProArgs A, char* __restrict__ ws) {
    __shared__ float ls[256], ls2[256];
    int b = blockIdx.x, tid = threadIdx.x;
    if (b < PRO_PACK) {
        // pack weights into MFMA fragment order (works as A- or B-operand):
        // frag(m,t,kt,lane) = W[n=t*16+(lane&15)][k=kt*32+(lane>>4)*8 + j], j=0..7
        unsigned short* dst = (unsigned short*)(ws + OFF_WPACK);
        int gid = b * 256 + tid;
        int m = gid >> 11, rem = gid & 2047;
        int t = rem >> 8, kt = (rem >> 6) & 3, lane = rem & 63;
        int n = t * 16 + (lane & 15);
        int k0 = kt * 32 + (lane >> 4) * 8;
        const float* wrow = A.w[m] + n * 128 + k0;
        float4 w0 = *(const float4*)wrow;
        float4 w1 = *(const float4*)(wrow + 4);
        ushort4 o0 = make_ushort4(f2bf(w0.x), f2bf(w0.y), f2bf(w0.z), f2bf(w0.w));
        ushort4 o1 = make_ushort4(f2bf(w1.x), f2bf(w1.y), f2bf(w1.z), f2bf(w1.w));
        *(ushort4*)(dst + (size_t)gid * 8)     = o0;
        *(ushort4*)(dst + (size_t)gid * 8 + 4) = o1;
    } else if (b < PRO_PACK + PRO_STAT) {
        int bb = b - PRO_PACK;
        int type = bb >> 8, xb = bb & 255;
        const float* x = type ? A.ft_user : A.ft_item;
        int N = type ? N_USER : N_ITEM;
        float* sum = (float*)(ws + OFF_STATS) + type * 256;
        float* sq  = sum + 128;
        int c = tid & 127;
        int half = tid >> 7;
        float s = 0.f, s2 = 0.f;
        for (int r = xb * 2 + half; r < N; r += 512) {
            float v = x[(size_t)r * 128 + c];
            s += v; s2 += v * v;
        }
        ls[tid] = s; ls2[tid] = s2;
        __syncthreads();
        if (half == 0) {
            atomicAdd(&sum[c], ls[c] + ls[c + 128]);
            atomicAdd(&sq[c],  ls2[c] + ls2[c + 128]);
        }
    } else {
        int e = (b - PRO_PACK - PRO_STAT) * 256 + tid;
        if (e < EALL) {
            int dst = (e < E1N) ? A.vid1[e] : A.vid2[e - E1N];
            atomicAdd((int*)(ws + OFF_HIST) + dst, 1);
        }
    }
}

// ---------------- scan_partial: per-1024-chunk exclusive scan --------------
__global__ __launch_bounds__(1024) void scan_partial(char* __restrict__ ws) {
    __shared__ int sd[1024];
    const int* hist = (const int*)(ws + OFF_HIST);
    int* start  = (int*)(ws + OFF_START);
    int* cursor = (int*)(ws + OFF_CURSOR);
    int* bsum   = (int*)(ws + OFF_BSUM);
    int t = threadIdx.x;
    int gid = blockIdx.x * 1024 + t;
    int v = hist[gid];
    sd[t] = v;
    __syncthreads();
    #pragma unroll
    for (int off = 1; off < 1024; off <<= 1) {
        int x = (t >= off) ? sd[t - off] : 0;
        __syncthreads();
        sd[t] += x;
        __syncthreads();
    }
    int ex = sd[t] - v;        // exclusive within chunk
    start[gid] = ex;
    cursor[gid] = ex;
    if (t == 1023) bsum[blockIdx.x] = sd[t];
}

// ---------------- mid: bn_finalize (block 0) + scan_top (block 1) ----------
__global__ __launch_bounds__(256) void mid(const float* __restrict__ g_i, const float* __restrict__ b_i,
                                           const float* __restrict__ g_u, const float* __restrict__ b_u,
                                           const float* __restrict__ ae1, const float* __restrict__ ae2,
                                           char* __restrict__ ws) {
    __shared__ int sd[128];
    int t = threadIdx.x;
    if (blockIdx.x == 0) {
        const float* stats = (const float*)(ws + OFF_STATS);
        float* scale = (float*)(ws + OFF_SCALE);
        float* M     = (float*)(ws + OFF_M);
        int type = t >> 7, c = t & 127;
        float N = type ? (float)N_USER : (float)N_ITEM;
        float su = stats[type * 256 + c];
        float sq = stats[type * 256 + 128 + c];
        float mu = su / N;
        float var = sq / N - mu * mu;
        float rstd = rsqrtf(var + 1e-5f);
        float g = type ? g_u[c] : g_i[c];
        float b = type ? b_u[c] : b_i[c];
        scale[type * 256 + c]       = g * rstd;
        scale[type * 256 + 128 + c] = b - mu * g * rstd;
        if (t < 8) {
            float m1 = 0.f, m2 = 0.f;
            for (int j = 0; j < 16; j++) {
                m1 += fmaxf(ae1[t * 16 + j], 0.f);
                m2 += fmaxf(ae2[t * 16 + j], 0.f);
            }
            M[t] = fmaxf(m1, m2);   // uniform per-head shift, both etypes
        }
    } else {
        int* bsum = (int*)(ws + OFF_BSUM);
        int v = 0;
        if (t < 128) { v = (t < 98) ? bsum[t] : 0; sd[t] = v; }
        __syncthreads();
        #pragma unroll
        for (int off = 1; off < 128; off <<= 1) {
            int x = 0;
            if (t < 128 && t >= off) x = sd[t - off];
            __syncthreads();
            if (t < 128) sd[t] += x;
            __syncthreads();
        }
        if (t < 98) bsum[t] = sd[t] - v;   // exclusive chunk offsets
    }
}

// ---------------- transposed MFMA transform body ---------------------------
// D[n][row] = sum_k W[n][k] * x[row][k]: A = packed W (frag layout), B = x rows.
// C/D: col(lane&15) = row index, rows(quad*4+reg) = 4 consecutive n ->
// contiguous per-lane stores, no LDS.
struct TArgs {
    const float* x;              // raw f32 features
    const float* bias0;          // bias for matrix 0 (q), may be null
    int N;
    int scaleOff;                // 0 item, 256 user
    int nmat;
    int wtIdx[5];
    unsigned short* out[5];
};

__device__ __forceinline__ void transform_body(const TArgs& A, char* __restrict__ ws, int blk) {
    const unsigned short* wpack = (const unsigned short*)(ws + OFF_WPACK);
    const float* scaleb = (const float*)(ws + OFF_SCALE) + A.scaleOff;
    int tid = threadIdx.x, lane = tid & 63, wv = tid >> 6;
    int l16 = lane & 15, quad = lane >> 4;
    int base = blk * 256 + wv * 64;

    // B-fragments: BN-applied feature rows (bf16), zero-padded beyond N
    bf16x8 bfr[4][4];
    #pragma unroll
    for (int kt = 0; kt < 4; kt++) {
        int c0 = kt * 32 + quad * 8;
        float4 sc0 = *(const float4*)(scaleb + c0);
        float4 sc1 = *(const float4*)(scaleb + c0 + 4);
        float4 bi0 = *(const float4*)(scaleb + 128 + c0);
        float4 bi1 = *(const float4*)(scaleb + 128 + c0 + 4);
        #pragma unroll
        for (int it = 0; it < 4; it++) {
            int gr = base + it * 16 + l16;
            bf16x8 f = {0, 0, 0, 0, 0, 0, 0, 0};
            if (gr < A.N) {
                const float* p = A.x + (size_t)gr * 128 + c0;
                float4 v0 = *(const float4*)p;
                float4 v1 = *(const float4*)(p + 4);
                f[0] = (short)f2bf(fmaf(v0.x, sc0.x, bi0.x));
                f[1] = (short)f2bf(fmaf(v0.y, sc0.y, bi0.y));
                f[2] = (short)f2bf(fmaf(v0.z, sc0.z, bi0.z));
                f[3] = (short)f2bf(fmaf(v0.w, sc0.w, bi0.w));
                f[4] = (short)f2bf(fmaf(v1.x, sc1.x, bi1.x));
                f[5] = (short)f2bf(fmaf(v1.y, sc1.y, bi1.y));
                f[6] = (short)f2bf(fmaf(v1.z, sc1.z, bi1.z));
                f[7] = (short)f2bf(fmaf(v1.w, sc1.w, bi1.w));
            }
            bfr[it][kt] = f;
        }
    }

    for (int m = 0; m < A.nmat; m++) {
        const unsigned short* wp = wpack + (size_t)A.wtIdx[m] * 16384;
        unsigned short* outp = A.out[m];
        const float* bias = (m == 0) ? A.bias0 : nullptr;
        #pragma unroll
        for (int nt = 0; nt < 8; nt++) {
            bf16x8 a4[4];
            #pragma unroll
            for (int kt = 0; kt < 4; kt++)
                a4[kt] = *(const bf16x8*)(wp + (size_t)((nt * 4 + kt) * 64 + lane) * 8);
            float4 bv = make_float4(0.f, 0.f, 0.f, 0.f);
            if (bias) bv = *(const float4*)(bias + nt * 16 + quad * 4);
            #pragma unroll
            for (int it = 0; it < 4; it++) {
                f32x4 acc = {bv.x, bv.y, bv.z, bv.w};
                #pragma unroll
                for (int kt = 0; kt < 4; kt++)
                    acc = __builtin_amdgcn_mfma_f32_16x16x32_bf16(a4[kt], bfr[it][kt], acc, 0, 0, 0);
                int row = base + it * 16 + l16;
                if (row < A.N) {
                    ushort4 o = make_ushort4(f2bf(acc[0]), f2bf(acc[1]), f2bf(acc[2]), f2bf(acc[3]));
                    *(ushort4*)(outp + (size_t)row * 128 + nt * 16 + quad * 4) = o;
                }
            }
        }
    }
}

// ---------------- mega: edge_scatter + item transforms + user transforms ---
struct MegaArgs {
    TArgs ti, tu;
    const int* uid1; const int* vid1; const int* cnt1;
    const int* uid2; const int* vid2;
};
#define MEGA_SCAT 2930
#define MEGA_T5 391
#define MEGA_T2 196

__global__ __launch_bounds__(256) void mega(MegaArgs A, char* __restrict__ ws) {
    int b = blockIdx.x;
    if (b < MEGA_SCAT) {
        int e = b * 256 + threadIdx.x;
        if (e >= EALL) return;
        int* cursor = (int*)(ws + OFF_CURSOR);
        const int* bsum = (const int*)(ws + OFF_BSUM);
        int2* ord = (int2*)(ws + OFF_ORD);
        int2 rec; int dst;
        if (e < E1N) {
            rec.x = A.uid1[e]; rec.y = A.cnt1[e]; dst = A.vid1[e];
        } else {
            int ee = e - E1N;
            rec.x = N_ITEM + A.uid2[ee]; rec.y = -1; dst = A.vid2[ee];
        }
        int pos = atomicAdd(&cursor[dst], 1) + bsum[dst >> 10];
        ord[pos] = rec;
    } else if (b < MEGA_SCAT + MEGA_T5) {
        transform_body(A.ti, ws, b - MEGA_SCAT);
    } else {
        transform_body(A.tu, ws, b - MEGA_SCAT - MEGA_T5);
    }
}

// ---------------- fused edge phase: wave per dst, 4 edges in flight --------
__global__ __launch_bounds__(256) void edge_agg(const float* __restrict__ emb,
                                                const float* __restrict__ ae1, const float* __restrict__ ae2,
                                                char* __restrict__ ws) {
    const unsigned short* qc = (const unsigned short*)(ws + OFF_QC);
    const unsigned short* vc = (const unsigned short*)(ws + OFF_VC);
    const unsigned short* k1 = (const unsigned short*)(ws + OFF_K1);
    const unsigned short* k2 = (const unsigned short*)(ws + OFF_K2);
    const int* start = (const int*)(ws + OFF_START);
    const int* bsum  = (const int*)(ws + OFF_BSUM);
    const int2* ord = (const int2*)(ws + OFF_ORD);
    const float* M = (const float*)(ws + OFF_M);
    float* agg = (float*)(ws + OFF_AGG);

    int tid = threadIdx.x;
    int lane = tid & 63;
    int half = lane >> 5;     // edge-slot within pair
    int l = lane & 31;
    int d0 = l << 2;          // 4 dims per lane
    int h = l >> 2;           // head
    int dst = blockIdx.x * 4 + (tid >> 6);
    if (dst >= N_ITEM) return;

    float mh = M[h];
    float4 ae1v = *(const float4*)(ae1 + d0);
    float4 ae2v = *(const float4*)(ae2 + d0);
    ushort4 k1p = *(const ushort4*)(k1 + (size_t)dst * 128 + d0);
    ushort4 k2p = *(const ushort4*)(k2 + (size_t)dst * 128 + d0);
    float4 k1v = make_float4(bf2f(k1p.x), bf2f(k1p.y), bf2f(k1p.z), bf2f(k1p.w));
    float4 k2v = make_float4(bf2f(k2p.x), bf2f(k2p.y), bf2f(k2p.z), bf2f(k2p.w));

    int beg = start[dst] + bsum[dst >> 10];
    int end = start[dst + 1] + bsum[(dst + 1) >> 10];
    float a0 = 0.f, a1 = 0.f, a2 = 0.f, a3 = 0.f, s = 0.f;

    for (int i = beg + half; i < end; i += 4) {
        int ib = i + 2;
        bool vb = ib < end;
        int2 ra = ord[i];
        int2 rb = ord[vb ? ib : i];
        bool t1a = ra.y >= 0, t1b = rb.y >= 0;
        // batch all loads up front (4 edges in flight per wave)
        ushort4 qa  = *(const ushort4*)(qc + (size_t)ra.x * 128 + d0);
        ushort4 qb  = *(const ushort4*)(qc + (size_t)rb.x * 128 + d0);
        ushort4 va4 = *(const ushort4*)(vc + (size_t)ra.x * 128 + d0);
        ushort4 vb4 = *(const ushort4*)(vc + (size_t)rb.x * 128 + d0);
        float4 eva = *(const float4*)(emb + (size_t)(t1a ? ra.y : 0) * 128 + d0);
        float4 evb = *(const float4*)(emb + (size_t)(t1b ? rb.y : 0) * 128 + d0);
        // edge a
        {
            float x0 = bf2f(qa.x) + (t1a ? k1v.x + eva.x : k2v.x);
            float x1 = bf2f(qa.y) + (t1a ? k1v.y + eva.y : k2v.y);
            float x2 = bf2f(qa.z) + (t1a ? k1v.z + eva.z : k2v.z);
            float x3 = bf2f(qa.w) + (t1a ? k1v.w + eva.w : k2v.w);
            float4 ae = t1a ? ae1v : ae2v;
            float t = ae.x * __builtin_amdgcn_rcpf(1.f + __expf(-x0))
                    + ae.y * __builtin_amdgcn_rcpf(1.f + __expf(-x1))
                    + ae.z * __builtin_amdgcn_rcpf(1.f + __expf(-x2))
                    + ae.w * __builtin_amdgcn_rcpf(1.f + __expf(-x3));
            t += __shfl_xor(t, 1);
            t += __shfl_xor(t, 2);
            float ex = __expf(t - mh);
            s += ex;
            a0 = fmaf(ex, bf2f(va4.x), a0);
            a1 = fmaf(ex, bf2f(va4.y), a1);
            a2 = fmaf(ex, bf2f(va4.z), a2);
            a3 = fmaf(ex, bf2f(va4.w), a3);
        }
        // edge b (masked if past end)
        {
            float x0 = bf2f(qb.x) + (t1b ? k1v.x + evb.x : k2v.x);
            float x1 = bf2f(qb.y) + (t1b ? k1v.y + evb.y : k2v.y);
            float x2 = bf2f(qb.z) + (t1b ? k1v.z + evb.z : k2v.z);
            float x3 = bf2f(qb.w) + (t1b ? k1v.w + evb.w : k2v.w);
            float4 ae = t1b ? ae1v : ae2v;
            float t = ae.x * __builtin_amdgcn_rcpf(1.f + __expf(-x0))
                    + ae.y * __builtin_amdgcn_rcpf(1.f + __expf(-x1))
                    + ae.z * __builtin_amdgcn_rcpf(1.f + __expf(-x2))
                    + ae.w * __builtin_amdgcn_rcpf(1.f + __expf(-x3));
            t += __shfl_xor(t, 1);
            t += __shfl_xor(t, 2);
            float ex = vb ? __expf(t - mh) : 0.f;
            s += ex;
            a0 = fmaf(ex, bf2f(vb4.x), a0);
            a1 = fmaf(ex, bf2f(vb4.y), a1);
            a2 = fmaf(ex, bf2f(vb4.z), a2);
            a3 = fmaf(ex, bf2f(vb4.w), a3);
        }
    }
    // combine the two half-wave streams
    s  += __shfl_xor(s, 32);
    a0 += __shfl_xor(a0, 32);
    a1 += __shfl_xor(a1, 32);
    a2 += __shfl_xor(a2, 32);
    a3 += __shfl_xor(a3, 32);
    if (half == 0) {
        float inv = (s > 0.f) ? (1.f / s) : 0.f;
        float4 o = make_float4(a0 * inv, a1 * inv, a2 * inv, a3 * inv);
        *(float4*)(agg + (size_t)dst * 128 + d0) = o;
    }
}

// ---------------- final: relu(agg @ Wagg.T + b + selfterm), transposed MFMA
__global__ __launch_bounds__(256) void final_mfma(const float* __restrict__ b_agg,
                                                  float* __restrict__ out, char* __restrict__ ws) {
    const float* agg = (const float*)(ws + OFF_AGG);
    const unsigned short* selft = (const unsigned short*)(ws + OFF_SELF);
    const unsigned short* wp = (const unsigned short*)(ws + OFF_WPACK) + 7ull * 16384;
    int tid = threadIdx.x, lane = tid & 63, wv = tid >> 6;
    int l16 = lane & 15, quad = lane >> 4;
    int base = blockIdx.x * 256 + wv * 64;

    // B-fragments from agg rows (f32 -> bf16)
    bf16x8 bfr[4][4];
    #pragma unroll
    for (int it = 0; it < 4; it++) {
        int gr = base + it * 16 + l16;
        #pragma unroll
        for (int kt = 0; kt < 4; kt++) {
            bf16x8 f = {0, 0, 0, 0, 0, 0, 0, 0};
            if (gr < N_ITEM) {
                const float* p = agg + (size_t)gr * 128 + kt * 32 + quad * 8;
                float4 v0 = *(const float4*)p;
                float4 v1 = *(const float4*)(p + 4);
                f[0] = (short)f2bf(v0.x); f[1] = (short)f2bf(v0.y);
                f[2] = (short)f2bf(v0.z); f[3] = (short)f2bf(v0.w);
                f[4] = (short)f2bf(v1.x); f[5] = (short)f2bf(v1.y);
                f[6] = (short)f2bf(v1.z); f[7] = (short)f2bf(v1.w);
            }
            bfr[it][kt] = f;
        }
    }

    #pragma unroll
    for (int nt = 0; nt < 8; nt++) {
        bf16x8 a4[4];
        #pragma unroll
        for (int kt = 0; kt < 4; kt++)
            a4[kt] = *(const bf16x8*)(wp + (size_t)((nt * 4 + kt) * 64 + lane) * 8);
        float4 bv = *(const float4*)(b_agg + nt * 16 + quad * 4);
        #pragma unroll
        for (int it = 0; it < 4; it++) {
            f32x4 acc = {bv.x, bv.y, bv.z, bv.w};
            #pragma unroll
            for (int kt = 0; kt < 4; kt++)
                acc = __builtin_amdgcn_mfma_f32_16x16x32_bf16(a4[kt], bfr[it][kt], acc, 0, 0, 0);
            int row = base + it * 16 + l16;
            if (row < N_ITEM) {
                size_t idx = (size_t)row * 128 + nt * 16 + quad * 4;
                ushort4 st = *(const ushort4*)(selft + idx);
                float4 o;
                o.x = fmaxf(acc[0] + bf2f(st.x), 0.f);
                o.y = fmaxf(acc[1] + bf2f(st.y), 0.f);
                o.z = fmaxf(acc[2] + bf2f(st.z), 0.f);
                o.w = fmaxf(acc[3] + bf2f(st.w), 0.f);
                *(float4*)(out + idx) = o;
            }
        }
    }
}

// ---------------- host ----------------
extern "C" void kernel_launch(void* const* d_in, const int* in_sizes, int n_in,
                              void* d_out, int out_size, void* d_ws, size_t ws_size,
                              hipStream_t stream) {
    char* ws = (char*)d_ws;

    const float* ft_item = (const float*)d_in[0];
    const float* ft_user = (const float*)d_in[1];
    const float* bng_i = (const float*)d_in[2];
    const float* bnb_i = (const float*)d_in[3];
    const float* bng_u = (const float*)d_in[4];
    const float* bnb_u = (const float*)d_in[5];
    const float* Wq1 = (const float*)d_in[6];
    const float* bq1 = (const float*)d_in[7];
    const float* Wk1 = (const float*)d_in[8];
    const float* Wv1 = (const float*)d_in[9];
    const float* ae1 = (const float*)d_in[10];
    const float* emb = (const float*)d_in[11];
    const float* Wq2 = (const float*)d_in[12];
    const float* bq2 = (const float*)d_in[13];
    const float* Wk2 = (const float*)d_in[14];
    const float* Wv2 = (const float*)d_in[15];
    const float* ae2 = (const float*)d_in[16];
    const float* W_agg = (const float*)d_in[17];
    const float* b_agg = (const float*)d_in[18];
    const float* W_self = (const float*)d_in[19];
    const int* uid1 = (const int*)d_in[20];
    const int* vid1 = (const int*)d_in[21];
    const int* cnt1 = (const int*)d_in[22];
    const int* uid2 = (const int*)d_in[23];
    const int* vid2 = (const int*)d_in[24];
    float* out = (float*)d_out;

    // single memset: stats (2KB) + hist (adjacent)
    hipMemsetAsync(ws + OFF_STATS, 0, 2048 + (size_t)NPAD * 4, stream);

    // 1. prologue: pack weights + BN stats + dst histogram
    ProArgs pa;
    pa.w[0] = Wq1; pa.w[1] = Wk1; pa.w[2] = Wv1; pa.w[3] = Wk2;
    pa.w[4] = W_self; pa.w[5] = Wq2; pa.w[6] = Wv2; pa.w[7] = W_agg;
    pa.ft_item = ft_item; pa.ft_user = ft_user;
    pa.vid1 = vid1; pa.vid2 = vid2;
    prologue<<<PRO_PACK + PRO_STAT + PRO_HIST, 256, 0, stream>>>(pa, ws);

    // 2. per-chunk exclusive scan
    scan_partial<<<98, 1024, 0, stream>>>(ws);

    // 3. BN finalize + chunk-offset scan
    mid<<<2, 256, 0, stream>>>(bng_i, bnb_i, bng_u, bnb_u, ae1, ae2, ws);

    // 4. mega: edge scatter + all 7 node-transform GEMMs
    MegaArgs ma;
    ma.ti.x = ft_item; ma.ti.bias0 = bq1; ma.ti.N = N_ITEM; ma.ti.scaleOff = 0; ma.ti.nmat = 5;
    ma.ti.wtIdx[0] = 0; ma.ti.wtIdx[1] = 1; ma.ti.wtIdx[2] = 2; ma.ti.wtIdx[3] = 3; ma.ti.wtIdx[4] = 4;
    unsigned short* QC = (unsigned short*)(ws + OFF_QC);
    unsigned short* VC = (unsigned short*)(ws + OFF_VC);
    ma.ti.out[0] = QC;
    ma.ti.out[1] = (unsigned short*)(ws + OFF_K1);
    ma.ti.out[2] = VC;
    ma.ti.out[3] = (unsigned short*)(ws + OFF_K2);
    ma.ti.out[4] = (unsigned short*)(ws + OFF_SELF);
    ma.tu.x = ft_user; ma.tu.bias0 = bq2; ma.tu.N = N_USER; ma.tu.scaleOff = 256; ma.tu.nmat = 2;
    ma.tu.wtIdx[0] = 5; ma.tu.wtIdx[1] = 6; ma.tu.wtIdx[2] = 0; ma.tu.wtIdx[3] = 0; ma.tu.wtIdx[4] = 0;
    ma.tu.out[0] = QC + (size_t)N_ITEM * 128;
    ma.tu.out[1] = VC + (size_t)N_ITEM * 128;
    ma.tu.out[2] = ma.tu.out[3] = ma.tu.out[4] = ma.tu.out[0];
    ma.uid1 = uid1; ma.vid1 = vid1; ma.cnt1 = cnt1; ma.uid2 = uid2; ma.vid2 = vid2;
    mega<<<MEGA_SCAT + MEGA_T5 + MEGA_T2, 256, 0, stream>>>(ma, ws);

    // 5. fused edge softmax+aggregate
    edge_agg<<<(N_ITEM + 3) / 4, 256, 0, stream>>>(emb, ae1, ae2, ws);

    // 6. final GEMM + self + relu
    final_mfma<<<NI_PAD / 256, 256, 0, stream>>>(b_agg, out, ws);
}

// Round 6
// 526.702 us; speedup vs baseline: 2.5510x; 1.0425x over previous
//
#include <hip/hip_runtime.h>
#include <hip/hip_bf16.h>

#define N_ITEM 100000
#define N_USER 50000
#define N_ALL  150000
#define E1N 500000
#define E2N 250000
#define EALL (E1N + E2N)
#define NPAD 100352          // 98 * 1024, >= N_ITEM+1
#define NI_PAD 100096        // 391 * 256
#define NU_PAD 50176         // 196 * 256

// ---------------- workspace layout (bytes) ----------------
static constexpr size_t OFF_STATS = 0;                       // 512 f32 (zeroed)
static constexpr size_t OFF_HIST  = 2048;                    // NPAD ints (zeroed, adjacent -> one memset)
static constexpr size_t OFF_SCALE = OFF_HIST + (size_t)NPAD * 4;       // 512 f32
static constexpr size_t OFF_M     = OFF_SCALE + 2048;                  // 8 f32
static constexpr size_t OFF_WPACK = 409600;                  // 8 matrices bf16 frag-packed
static constexpr size_t OFF_QC    = OFF_WPACK + 8ull * 32768ull;       // bf16 [N_ALL,128] q1|q2
static constexpr size_t OFF_VC    = OFF_QC + (size_t)N_ALL * 256;      // bf16 v1|v2
static constexpr size_t OFF_K1    = OFF_VC + (size_t)N_ALL * 256;
static constexpr size_t OFF_K2    = OFF_K1 + (size_t)N_ITEM * 256;
static constexpr size_t OFF_SELF  = OFF_K2 + (size_t)N_ITEM * 256;
static constexpr size_t OFF_START = OFF_SELF + (size_t)N_ITEM * 256;   // NPAD ints (within-chunk exclusive)
static constexpr size_t OFF_CURSOR= OFF_START + (size_t)NPAD * 4;      // NPAD ints
static constexpr size_t OFF_BSUM  = OFF_CURSOR + (size_t)NPAD * 4;     // 128 ints
static constexpr size_t OFF_ORD   = OFF_BSUM + 1024;                   // EALL int2
static constexpr size_t OFF_AGG   = OFF_ORD + (size_t)EALL * 8 + 128;  // f32 [N_ITEM,128]

// ---------------- helpers ----------------
__device__ __forceinline__ float bf2f(unsigned short u) {
    return __uint_as_float(((unsigned)u) << 16);
}
__device__ __forceinline__ unsigned short f2bf(float f) {
    unsigned u = __float_as_uint(f);
    u += 0x7fffu + ((u >> 16) & 1u);   // round-to-nearest-even
    return (unsigned short)(u >> 16);
}

typedef __attribute__((ext_vector_type(8))) short bf16x8;
typedef __attribute__((ext_vector_type(4))) float f32x4;

// ---------------- prologue: pack_w + bn_stats + edge_hist in one grid ------
struct ProArgs {
    const float* w[8];
    const float* ft_item;
    const float* ft_user;
    const int* vid1;
    const int* vid2;
};
#define PRO_PACK 64
#define PRO_STAT 512
#define PRO_HIST 2930   // ceil(EALL/256)

__global__ __launch_bounds__(256) void prologue(ProArgs A, char* __restrict__ ws) {
    __shared__ float ls[256], ls2[256];
    int b = blockIdx.x, tid = threadIdx.x;
    if (b < PRO_PACK) {
        // pack weights into MFMA fragment order:
        // frag(m,t,kt,lane) = W[n=t*16+(lane&15)][k=kt*32+(lane>>4)*8 + j], j=0..7
        unsigned short* dst = (unsigned short*)(ws + OFF_WPACK);
        int gid = b * 256 + tid;
        int m = gid >> 11, rem = gid & 2047;
        int t = rem >> 8, kt = (rem >> 6) & 3, lane = rem & 63;
        int n = t * 16 + (lane & 15);
        int k0 = kt * 32 + (lane >> 4) * 8;
        const float* wrow = A.w[m] + n * 128 + k0;
        float4 w0 = *(const float4*)wrow;
        float4 w1 = *(const float4*)(wrow + 4);
        ushort4 o0 = make_ushort4(f2bf(w0.x), f2bf(w0.y), f2bf(w0.z), f2bf(w0.w));
        ushort4 o1 = make_ushort4(f2bf(w1.x), f2bf(w1.y), f2bf(w1.z), f2bf(w1.w));
        *(ushort4*)(dst + (size_t)gid * 8)     = o0;
        *(ushort4*)(dst + (size_t)gid * 8 + 4) = o1;
    } else if (b < PRO_PACK + PRO_STAT) {
        int bb = b - PRO_PACK;
        int type = bb >> 8, xb = bb & 255;
        const float* x = type ? A.ft_user : A.ft_item;
        int N = type ? N_USER : N_ITEM;
        float* sum = (float*)(ws + OFF_STATS) + type * 256;
        float* sq  = sum + 128;
        int c = tid & 127;
        int half = tid >> 7;
        float s = 0.f, s2 = 0.f;
        for (int r = xb * 2 + half; r < N; r += 512) {
            float v = x[(size_t)r * 128 + c];
            s += v; s2 += v * v;
        }
        ls[tid] = s; ls2[tid] = s2;
        __syncthreads();
        if (half == 0) {
            atomicAdd(&sum[c], ls[c] + ls[c + 128]);
            atomicAdd(&sq[c],  ls2[c] + ls2[c + 128]);
        }
    } else {
        int e = (b - PRO_PACK - PRO_STAT) * 256 + tid;
        if (e < EALL) {
            int dst = (e < E1N) ? A.vid1[e] : A.vid2[e - E1N];
            atomicAdd((int*)(ws + OFF_HIST) + dst, 1);
        }
    }
}

// ---------------- scan_partial: per-1024-chunk exclusive scan --------------
__global__ __launch_bounds__(1024) void scan_partial(char* __restrict__ ws) {
    __shared__ int sd[1024];
    const int* hist = (const int*)(ws + OFF_HIST);
    int* start  = (int*)(ws + OFF_START);
    int* cursor = (int*)(ws + OFF_CURSOR);
    int* bsum   = (int*)(ws + OFF_BSUM);
    int t = threadIdx.x;
    int gid = blockIdx.x * 1024 + t;
    int v = hist[gid];
    sd[t] = v;
    __syncthreads();
    #pragma unroll
    for (int off = 1; off < 1024; off <<= 1) {
        int x = (t >= off) ? sd[t - off] : 0;
        __syncthreads();
        sd[t] += x;
        __syncthreads();
    }
    int ex = sd[t] - v;        // exclusive within chunk
    start[gid] = ex;
    cursor[gid] = ex;
    if (t == 1023) bsum[blockIdx.x] = sd[t];
}

// ---------------- mid: bn_finalize (block 0) + scan_top (block 1) ----------
__global__ __launch_bounds__(256) void mid(const float* __restrict__ g_i, const float* __restrict__ b_i,
                                           const float* __restrict__ g_u, const float* __restrict__ b_u,
                                           const float* __restrict__ ae1, const float* __restrict__ ae2,
                                           char* __restrict__ ws) {
    __shared__ int sd[128];
    int t = threadIdx.x;
    if (blockIdx.x == 0) {
        const float* stats = (const float*)(ws + OFF_STATS);
        float* scale = (float*)(ws + OFF_SCALE);
        float* M     = (float*)(ws + OFF_M);
        int type = t >> 7, c = t & 127;
        float N = type ? (float)N_USER : (float)N_ITEM;
        float su = stats[type * 256 + c];
        float sq = stats[type * 256 + 128 + c];
        float mu = su / N;
        float var = sq / N - mu * mu;
        float rstd = rsqrtf(var + 1e-5f);
        float g = type ? g_u[c] : g_i[c];
        float b = type ? b_u[c] : b_i[c];
        scale[type * 256 + c]       = g * rstd;
        scale[type * 256 + 128 + c] = b - mu * g * rstd;
        if (t < 8) {
            float m1 = 0.f, m2 = 0.f;
            for (int j = 0; j < 16; j++) {
                m1 += fmaxf(ae1[t * 16 + j], 0.f);
                m2 += fmaxf(ae2[t * 16 + j], 0.f);
            }
            M[t] = fmaxf(m1, m2);   // uniform per-head shift, both etypes
        }
    } else {
        int* bsum = (int*)(ws + OFF_BSUM);
        int v = 0;
        if (t < 128) { v = (t < 98) ? bsum[t] : 0; sd[t] = v; }
        __syncthreads();
        #pragma unroll
        for (int off = 1; off < 128; off <<= 1) {
            int x = 0;
            if (t < 128 && t >= off) x = sd[t - off];
            __syncthreads();
            if (t < 128) sd[t] += x;
            __syncthreads();
        }
        if (t < 98) bsum[t] = sd[t] - v;   // exclusive chunk offsets
    }
}

// ---------------- edge scatter (separate for attribution) ------------------
__global__ __launch_bounds__(256) void edge_scatter(const int* __restrict__ uid1, const int* __restrict__ vid1,
                                                    const int* __restrict__ cnt1,
                                                    const int* __restrict__ uid2, const int* __restrict__ vid2,
                                                    char* __restrict__ ws) {
    int e = blockIdx.x * 256 + threadIdx.x;
    if (e >= EALL) return;
    int* cursor = (int*)(ws + OFF_CURSOR);
    const int* bsum = (const int*)(ws + OFF_BSUM);
    int2* ord = (int2*)(ws + OFF_ORD);
    int2 rec; int dst;
    if (e < E1N) {
        rec.x = uid1[e]; rec.y = cnt1[e]; dst = vid1[e];
    } else {
        int ee = e - E1N;
        rec.x = N_ITEM + uid2[ee]; rec.y = -1; dst = vid2[ee];
    }
    int pos = atomicAdd(&cursor[dst], 1) + bsum[dst >> 10];
    ord[pos] = rec;
}

// ---------------- transform: transposed MFMA + per-wave LDS store stage ----
// D[n][row] = sum_k W[n][k]*x[row][k]; A-op = packed W, B-op = BN'd x rows.
// C/D: col(lane&15)=row, 4 regs = 4 consecutive n. Stores staged through a
// per-wave 16x136 LDS tile (DS ops are in-order per wave; no barrier needed)
// and written back as lane-contiguous bf16x8 -> fully coalesced rows.
struct TArgs {
    const float* x;              // raw f32 features
    const float* bias0;          // bias for matrix 0 (q), may be null
    int N;
    int scaleOff;                // 0 item, 256 user
    int nmat;
    int wtIdx[5];
    unsigned short* out[5];
};

#define TB_I 391
#define TB_U 196
#define SPITCH 136

__global__ __launch_bounds__(256) void transform(TArgs AI, TArgs AU, char* __restrict__ ws) {
    __shared__ unsigned short stg[4][2][16 * SPITCH];
    int b = blockIdx.x;
    const TArgs& A = (b < TB_I) ? AI : AU;
    int blk = (b < TB_I) ? b : b - TB_I;

    const unsigned short* wpack = (const unsigned short*)(ws + OFF_WPACK);
    const float* scaleb = (const float*)(ws + OFF_SCALE) + A.scaleOff;
    int tid = threadIdx.x, lane = tid & 63, wv = tid >> 6;
    int l16 = lane & 15, quad = lane >> 4;
    int base = blk * 256 + wv * 64;

    // B-fragments: BN-applied feature rows (bf16), zero-padded beyond N
    bf16x8 bfr[4][4];
    #pragma unroll
    for (int kt = 0; kt < 4; kt++) {
        int c0 = kt * 32 + quad * 8;
        float4 sc0 = *(const float4*)(scaleb + c0);
        float4 sc1 = *(const float4*)(scaleb + c0 + 4);
        float4 bi0 = *(const float4*)(scaleb + 128 + c0);
        float4 bi1 = *(const float4*)(scaleb + 128 + c0 + 4);
        #pragma unroll
        for (int it = 0; it < 4; it++) {
            int gr = base + it * 16 + l16;
            bf16x8 f = {0, 0, 0, 0, 0, 0, 0, 0};
            if (gr < A.N) {
                const float* p = A.x + (size_t)gr * 128 + c0;
                float4 v0 = *(const float4*)p;
                float4 v1 = *(const float4*)(p + 4);
                f[0] = (short)f2bf(fmaf(v0.x, sc0.x, bi0.x));
                f[1] = (short)f2bf(fmaf(v0.y, sc0.y, bi0.y));
                f[2] = (short)f2bf(fmaf(v0.z, sc0.z, bi0.z));
                f[3] = (short)f2bf(fmaf(v0.w, sc0.w, bi0.w));
                f[4] = (short)f2bf(fmaf(v1.x, sc1.x, bi1.x));
                f[5] = (short)f2bf(fmaf(v1.y, sc1.y, bi1.y));
                f[6] = (short)f2bf(fmaf(v1.z, sc1.z, bi1.z));
                f[7] = (short)f2bf(fmaf(v1.w, sc1.w, bi1.w));
            }
            bfr[it][kt] = f;
        }
    }

    for (int m = 0; m < A.nmat; m++) {
        const unsigned short* wp = wpack + (size_t)A.wtIdx[m] * 16384;
        unsigned short* outp = A.out[m];
        const float* bias = (m == 0) ? A.bias0 : nullptr;
        #pragma unroll
        for (int it = 0; it < 4; it++) {
            unsigned short* st = stg[wv][it & 1];
            #pragma unroll
            for (int nt = 0; nt < 8; nt++) {
                bf16x8 a4[4];
                #pragma unroll
                for (int kt = 0; kt < 4; kt++)
                    a4[kt] = *(const bf16x8*)(wp + (size_t)((nt * 4 + kt) * 64 + lane) * 8);
                f32x4 acc = {0.f, 0.f, 0.f, 0.f};
                if (bias) {
                    float4 bv = *(const float4*)(bias + nt * 16 + quad * 4);
                    acc[0] = bv.x; acc[1] = bv.y; acc[2] = bv.z; acc[3] = bv.w;
                }
                #pragma unroll
                for (int kt = 0; kt < 4; kt++)
                    acc = __builtin_amdgcn_mfma_f32_16x16x32_bf16(a4[kt], bfr[it][kt], acc, 0, 0, 0);
                ushort4 o = make_ushort4(f2bf(acc[0]), f2bf(acc[1]), f2bf(acc[2]), f2bf(acc[3]));
                *(ushort4*)(st + l16 * SPITCH + nt * 16 + quad * 4) = o;
            }
            // wave-synchronous readback -> coalesced stores (no __syncthreads)
            #pragma unroll
            for (int i = 0; i < 4; i++) {
                int chunk = i * 64 + lane;
                int row = chunk >> 4, c8 = (chunk & 15) * 8;
                int gr = base + it * 16 + row;
                if (gr < A.N)
                    *(bf16x8*)(outp + (size_t)gr * 128 + c8) = *(const bf16x8*)(st + row * SPITCH + c8);
            }
        }
    }
}

// ---------------- fused edge phase: wave per dst, 16 lanes/edge ------------
__global__ __launch_bounds__(256) void edge_agg(const float* __restrict__ emb,
                                                const float* __restrict__ ae1, const float* __restrict__ ae2,
                                                char* __restrict__ ws) {
    const unsigned short* qc = (const unsigned short*)(ws + OFF_QC);
    const unsigned short* vc = (const unsigned short*)(ws + OFF_VC);
    const unsigned short* k1 = (const unsigned short*)(ws + OFF_K1);
    const unsigned short* k2 = (const unsigned short*)(ws + OFF_K2);
    const int* start = (const int*)(ws + OFF_START);
    const int* bsum  = (const int*)(ws + OFF_BSUM);
    const int2* ord = (const int2*)(ws + OFF_ORD);
    const float* M = (const float*)(ws + OFF_M);
    float* agg = (float*)(ws + OFF_AGG);

    int tid = threadIdx.x;
    int lane = tid & 63;
    int slot = lane >> 4;     // 4 edge slots per wave
    int l16 = lane & 15;
    int d0 = l16 * 8;         // 8 dims per lane
    int h = l16 >> 1;         // head (16 dims = 2 lanes)
    int dst = blockIdx.x * 4 + (tid >> 6);
    if (dst >= N_ITEM) return;

    float mh = M[h];
    float ae1f[8], ae2f[8], k1f[8], k2f[8];
    {
        float4 a0 = *(const float4*)(ae1 + d0), a1 = *(const float4*)(ae1 + d0 + 4);
        float4 b0 = *(const float4*)(ae2 + d0), b1 = *(const float4*)(ae2 + d0 + 4);
        ae1f[0]=a0.x; ae1f[1]=a0.y; ae1f[2]=a0.z; ae1f[3]=a0.w;
        ae1f[4]=a1.x; ae1f[5]=a1.y; ae1f[6]=a1.z; ae1f[7]=a1.w;
        ae2f[0]=b0.x; ae2f[1]=b0.y; ae2f[2]=b0.z; ae2f[3]=b0.w;
        ae2f[4]=b1.x; ae2f[5]=b1.y; ae2f[6]=b1.z; ae2f[7]=b1.w;
        bf16x8 p1 = *(const bf16x8*)(k1 + (size_t)dst * 128 + d0);
        bf16x8 p2 = *(const bf16x8*)(k2 + (size_t)dst * 128 + d0);
        #pragma unroll
        for (int j = 0; j < 8; j++) {
            k1f[j] = bf2f((unsigned short)p1[j]);
            k2f[j] = bf2f((unsigned short)p2[j]);
        }
    }

    int beg = start[dst] + bsum[dst >> 10];
    int end = start[dst + 1] + bsum[(dst + 1) >> 10];
    float acc[8];
    #pragma unroll
    for (int j = 0; j < 8; j++) acc[j] = 0.f;
    float s = 0.f;

    for (int i = beg + slot; i < end; i += 8) {
        int i2 = i + 4;
        bool vb = i2 < end;
        int2 ra = ord[i];
        int2 rb = ord[vb ? i2 : i];
        bool t1a = ra.y >= 0, t1b = rb.y >= 0;
        // batch gathers: 8 edges in flight per wave
        bf16x8 qa = *(const bf16x8*)(qc + (size_t)ra.x * 128 + d0);
        bf16x8 qb = *(const bf16x8*)(qc + (size_t)rb.x * 128 + d0);
        bf16x8 va = *(const bf16x8*)(vc + (size_t)ra.x * 128 + d0);
        bf16x8 vbv = *(const bf16x8*)(vc + (size_t)rb.x * 128 + d0);
        const float* epa = emb + (size_t)(t1a ? ra.y : 0) * 128 + d0;
        const float* epb = emb + (size_t)(t1b ? rb.y : 0) * 128 + d0;
        float4 ea0 = *(const float4*)epa, ea1 = *(const float4*)(epa + 4);
        float4 eb0 = *(const float4*)epb, eb1 = *(const float4*)(epb + 4);
        float eaf[8] = {ea0.x, ea0.y, ea0.z, ea0.w, ea1.x, ea1.y, ea1.z, ea1.w};
        float ebf[8] = {eb0.x, eb0.y, eb0.z, eb0.w, eb1.x, eb1.y, eb1.z, eb1.w};
        // edge a
        {
            float t = 0.f;
            #pragma unroll
            for (int j = 0; j < 8; j++) {
                float x = bf2f((unsigned short)qa[j]) + (t1a ? k1f[j] + eaf[j] : k2f[j]);
                float ae = t1a ? ae1f[j] : ae2f[j];
                t += ae * __builtin_amdgcn_rcpf(1.f + __expf(-x));
            }
            t += __shfl_xor(t, 1);
            float ex = __expf(t - mh);
            s += ex;
            #pragma unroll
            for (int j = 0; j < 8; j++)
                acc[j] = fmaf(ex, bf2f((unsigned short)va[j]), acc[j]);
        }
        // edge b (masked)
        {
            float t = 0.f;
            #pragma unroll
            for (int j = 0; j < 8; j++) {
                float x = bf2f((unsigned short)qb[j]) + (t1b ? k1f[j] + ebf[j] : k2f[j]);
                float ae = t1b ? ae1f[j] : ae2f[j];
                t += ae * __builtin_amdgcn_rcpf(1.f + __expf(-x));
            }
            t += __shfl_xor(t, 1);
            float ex = vb ? __expf(t - mh) : 0.f;
            s += ex;
            #pragma unroll
            for (int j = 0; j < 8; j++)
                acc[j] = fmaf(ex, bf2f((unsigned short)vbv[j]), acc[j]);
        }
    }
    // combine the four slots
    s += __shfl_xor(s, 16);
    s += __shfl_xor(s, 32);
    #pragma unroll
    for (int j = 0; j < 8; j++) {
        acc[j] += __shfl_xor(acc[j], 16);
        acc[j] += __shfl_xor(acc[j], 32);
    }
    if (slot == 0) {
        float inv = (s > 0.f) ? __builtin_amdgcn_rcpf(s) : 0.f;
        float4 o0 = make_float4(acc[0] * inv, acc[1] * inv, acc[2] * inv, acc[3] * inv);
        float4 o1 = make_float4(acc[4] * inv, acc[5] * inv, acc[6] * inv, acc[7] * inv);
        *(float4*)(agg + (size_t)dst * 128 + d0)     = o0;
        *(float4*)(agg + (size_t)dst * 128 + d0 + 4) = o1;
    }
}

// ---------------- final: relu(agg @ Wagg.T + b + selfterm), LDS-staged -----
#define FPITCH 132

__global__ __launch_bounds__(256) void final_mfma(const float* __restrict__ b_agg,
                                                  float* __restrict__ out, char* __restrict__ ws) {
    __shared__ float stg[4][16 * FPITCH];
    const float* agg = (const float*)(ws + OFF_AGG);
    const unsigned short* selft = (const unsigned short*)(ws + OFF_SELF);
    const unsigned short* wp = (const unsigned short*)(ws + OFF_WPACK) + 7ull * 16384;
    int tid = threadIdx.x, lane = tid & 63, wv = tid >> 6;
    int l16 = lane & 15, quad = lane >> 4;
    int base = blockIdx.x * 256 + wv * 64;
    float* st = stg[wv];

    // B-fragments from agg rows (f32 -> bf16)
    bf16x8 bfr[4][4];
    #pragma unroll
    for (int it = 0; it < 4; it++) {
        int gr = base + it * 16 + l16;
        #pragma unroll
        for (int kt = 0; kt < 4; kt++) {
            bf16x8 f = {0, 0, 0, 0, 0, 0, 0, 0};
            if (gr < N_ITEM) {
                const float* p = agg + (size_t)gr * 128 + kt * 32 + quad * 8;
                float4 v0 = *(const float4*)p;
                float4 v1 = *(const float4*)(p + 4);
                f[0] = (short)f2bf(v0.x); f[1] = (short)f2bf(v0.y);
                f[2] = (short)f2bf(v0.z); f[3] = (short)f2bf(v0.w);
                f[4] = (short)f2bf(v1.x); f[5] = (short)f2bf(v1.y);
                f[6] = (short)f2bf(v1.z); f[7] = (short)f2bf(v1.w);
            }
            bfr[it][kt] = f;
        }
    }

    #pragma unroll
    for (int it = 0; it < 4; it++) {
        #pragma unroll
        for (int nt = 0; nt < 8; nt++) {
            bf16x8 a4[4];
            #pragma unroll
            for (int kt = 0; kt < 4; kt++)
                a4[kt] = *(const bf16x8*)(wp + (size_t)((nt * 4 + kt) * 64 + lane) * 8);
            float4 bv = *(const float4*)(b_agg + nt * 16 + quad * 4);
            f32x4 acc = {bv.x, bv.y, bv.z, bv.w};
            #pragma unroll
            for (int kt = 0; kt < 4; kt++)
                acc = __builtin_amdgcn_mfma_f32_16x16x32_bf16(a4[kt], bfr[it][kt], acc, 0, 0, 0);
            *(f32x4*)(st + l16 * FPITCH + nt * 16 + quad * 4) = acc;
        }
        // wave-synchronous readback: coalesced add-self + relu + store
        #pragma unroll
        for (int i = 0; i < 8; i++) {
            int chunk = i * 64 + lane;
            int row = chunk >> 5, c4 = (chunk & 31) * 4;
            int gr = base + it * 16 + row;
            if (gr < N_ITEM) {
                float4 v = *(const float4*)(st + row * FPITCH + c4);
                size_t idx = (size_t)gr * 128 + c4;
                ushort4 sf = *(const ushort4*)(selft + idx);
                float4 o;
                o.x = fmaxf(v.x + bf2f(sf.x), 0.f);
                o.y = fmaxf(v.y + bf2f(sf.y), 0.f);
                o.z = fmaxf(v.z + bf2f(sf.z), 0.f);
                o.w = fmaxf(v.w + bf2f(sf.w), 0.f);
                *(float4*)(out + idx) = o;
            }
        }
    }
}

// ---------------- host ----------------
extern "C" void kernel_launch(void* const* d_in, const int* in_sizes, int n_in,
                              void* d_out, int out_size, void* d_ws, size_t ws_size,
                              hipStream_t stream) {
    char* ws = (char*)d_ws;

    const float* ft_item = (const float*)d_in[0];
    const float* ft_user = (const float*)d_in[1];
    const float* bng_i = (const float*)d_in[2];
    const float* bnb_i = (const float*)d_in[3];
    const float* bng_u = (const float*)d_in[4];
    const float* bnb_u = (const float*)d_in[5];
    const float* Wq1 = (const float*)d_in[6];
    const float* bq1 = (const float*)d_in[7];
    const float* Wk1 = (const float*)d_in[8];
    const float* Wv1 = (const float*)d_in[9];
    const float* ae1 = (const float*)d_in[10];
    const float* emb = (const float*)d_in[11];
    const float* Wq2 = (const float*)d_in[12];
    const float* bq2 = (const float*)d_in[13];
    const float* Wk2 = (const float*)d_in[14];
    const float* Wv2 = (const float*)d_in[15];
    const float* ae2 = (const float*)d_in[16];
    const float* W_agg = (const float*)d_in[17];
    const float* b_agg = (const float*)d_in[18];
    const float* W_self = (const float*)d_in[19];
    const int* uid1 = (const int*)d_in[20];
    const int* vid1 = (const int*)d_in[21];
    const int* cnt1 = (const int*)d_in[22];
    const int* uid2 = (const int*)d_in[23];
    const int* vid2 = (const int*)d_in[24];
    float* out = (float*)d_out;

    // single memset: stats (2KB) + hist (adjacent)
    hipMemsetAsync(ws + OFF_STATS, 0, 2048 + (size_t)NPAD * 4, stream);

    // 1. prologue: pack weights + BN stats + dst histogram
    ProArgs pa;
    pa.w[0] = Wq1; pa.w[1] = Wk1; pa.w[2] = Wv1; pa.w[3] = Wk2;
    pa.w[4] = W_self; pa.w[5] = Wq2; pa.w[6] = Wv2; pa.w[7] = W_agg;
    pa.ft_item = ft_item; pa.ft_user = ft_user;
    pa.vid1 = vid1; pa.vid2 = vid2;
    prologue<<<PRO_PACK + PRO_STAT + PRO_HIST, 256, 0, stream>>>(pa, ws);

    // 2. per-chunk exclusive scan
    scan_partial<<<98, 1024, 0, stream>>>(ws);

    // 3. BN finalize + chunk-offset scan
    mid<<<2, 256, 0, stream>>>(bng_i, bnb_i, bng_u, bnb_u, ae1, ae2, ws);

    // 4. edge scatter (CSR records)
    edge_scatter<<<(EALL + 255) / 256, 256, 0, stream>>>(uid1, vid1, cnt1, uid2, vid2, ws);

    // 5. all 7 node-transform GEMMs (item range + user range)
    TArgs ti, tu;
    ti.x = ft_item; ti.bias0 = bq1; ti.N = N_ITEM; ti.scaleOff = 0; ti.nmat = 5;
    ti.wtIdx[0] = 0; ti.wtIdx[1] = 1; ti.wtIdx[2] = 2; ti.wtIdx[3] = 3; ti.wtIdx[4] = 4;
    unsigned short* QC = (unsigned short*)(ws + OFF_QC);
    unsigned short* VC = (unsigned short*)(ws + OFF_VC);
    ti.out[0] = QC;
    ti.out[1] = (unsigned short*)(ws + OFF_K1);
    ti.out[2] = VC;
    ti.out[3] = (unsigned short*)(ws + OFF_K2);
    ti.out[4] = (unsigned short*)(ws + OFF_SELF);
    tu.x = ft_user; tu.bias0 = bq2; tu.N = N_USER; tu.scaleOff = 256; tu.nmat = 2;
    tu.wtIdx[0] = 5; tu.wtIdx[1] = 6; tu.wtIdx[2] = 0; tu.wtIdx[3] = 0; tu.wtIdx[4] = 0;
    tu.out[0] = QC + (size_t)N_ITEM * 128;
    tu.out[1] = VC + (size_t)N_ITEM * 128;
    tu.out[2] = tu.out[3] = tu.out[4] = tu.out[0];
    transform<<<TB_I + TB_U, 256, 0, stream>>>(ti, tu, ws);

    // 6. fused edge softmax+aggregate
    edge_agg<<<(N_ITEM + 3) / 4, 256, 0, stream>>>(emb, ae1, ae2, ws);

    // 7. final GEMM + self + relu
    final_mfma<<<NI_PAD / 256, 256, 0, stream>>>(b_agg, out, ws);
}

// Round 7
// 511.082 us; speedup vs baseline: 2.6289x; 1.0306x over previous
//
#include <hip/hip_runtime.h>
#include <hip/hip_bf16.h>

#define N_ITEM 100000
#define N_USER 50000
#define N_ALL  150000
#define E1N 500000
#define E2N 250000
#define EALL (E1N + E2N)
#define NPAD 100352          // 98 * 1024, >= N_ITEM+1

// ---------------- workspace layout (bytes) ----------------
static constexpr size_t OFF_STATS = 0;                       // 512 f32 (zeroed)
static constexpr size_t OFF_HIST  = 2048;                    // NPAD ints (zeroed, adjacent -> one memset)
static constexpr size_t OFF_SCALE = OFF_HIST + (size_t)NPAD * 4;       // 512 f32
static constexpr size_t OFF_M     = OFF_SCALE + 2048;                  // 8 f32
static constexpr size_t OFF_EMBB  = OFF_M + 64;                        // bf16 emb [51,128] = 13056 B
static constexpr size_t OFF_WPACK = OFF_EMBB + 13312;        // 8 matrices bf16 frag-packed
static constexpr size_t OFF_QC    = OFF_WPACK + 8ull * 32768ull;       // bf16 [N_ALL,128] q1|q2
static constexpr size_t OFF_VC    = OFF_QC + (size_t)N_ALL * 256;      // bf16 v1|v2
static constexpr size_t OFF_K1    = OFF_VC + (size_t)N_ALL * 256;
static constexpr size_t OFF_K2    = OFF_K1 + (size_t)N_ITEM * 256;
static constexpr size_t OFF_SELF  = OFF_K2 + (size_t)N_ITEM * 256;
static constexpr size_t OFF_START = OFF_SELF + (size_t)N_ITEM * 256;   // NPAD ints (within-chunk exclusive)
static constexpr size_t OFF_CURSOR= OFF_START + (size_t)NPAD * 4;      // NPAD ints
static constexpr size_t OFF_BSUM  = OFF_CURSOR + (size_t)NPAD * 4;     // 128 ints
static constexpr size_t OFF_ORD   = OFF_BSUM + 1024;                   // EALL int2
static constexpr size_t OFF_AGG   = OFF_ORD + (size_t)EALL * 8 + 128;  // f32 [N_ITEM,128]

// ---------------- helpers ----------------
__device__ __forceinline__ float bf2f(unsigned short u) {
    return __uint_as_float(((unsigned)u) << 16);
}
__device__ __forceinline__ unsigned short f2bf(float f) {
    unsigned u = __float_as_uint(f);
    u += 0x7fffu + ((u >> 16) & 1u);   // round-to-nearest-even
    return (unsigned short)(u >> 16);
}

typedef __attribute__((ext_vector_type(8))) short bf16x8;
typedef __attribute__((ext_vector_type(4))) float f32x4;

// ---------------- prologue: pack_w + emb->bf16 + bn_stats + edge_hist ------
struct ProArgs {
    const float* w[8];
    const float* ft_item;
    const float* ft_user;
    const float* emb;
    const int* vid1;
    const int* vid2;
};
#define PRO_PACK 64
#define PRO_EMB  7      // 51*128/4 = 1632 threads
#define PRO_STAT 512
#define PRO_HIST 2930   // ceil(EALL/256)

__global__ __launch_bounds__(256) void prologue(ProArgs A, char* __restrict__ ws) {
    __shared__ float ls[256], ls2[256];
    int b = blockIdx.x, tid = threadIdx.x;
    if (b < PRO_PACK) {
        // pack weights into MFMA fragment order:
        // frag(m,t,kt,lane) = W[n=t*16+(lane&15)][k=kt*32+(lane>>4)*8 + j], j=0..7
        unsigned short* dst = (unsigned short*)(ws + OFF_WPACK);
        int gid = b * 256 + tid;
        int m = gid >> 11, rem = gid & 2047;
        int t = rem >> 8, kt = (rem >> 6) & 3, lane = rem & 63;
        int n = t * 16 + (lane & 15);
        int k0 = kt * 32 + (lane >> 4) * 8;
        const float* wrow = A.w[m] + n * 128 + k0;
        float4 w0 = *(const float4*)wrow;
        float4 w1 = *(const float4*)(wrow + 4);
        ushort4 o0 = make_ushort4(f2bf(w0.x), f2bf(w0.y), f2bf(w0.z), f2bf(w0.w));
        ushort4 o1 = make_ushort4(f2bf(w1.x), f2bf(w1.y), f2bf(w1.z), f2bf(w1.w));
        *(ushort4*)(dst + (size_t)gid * 8)     = o0;
        *(ushort4*)(dst + (size_t)gid * 8 + 4) = o1;
    } else if (b < PRO_PACK + PRO_EMB) {
        int gid = (b - PRO_PACK) * 256 + tid;   // one thread = 4 elems
        if (gid * 4 < 51 * 128) {
            float4 v = *(const float4*)(A.emb + gid * 4);
            ushort4 o = make_ushort4(f2bf(v.x), f2bf(v.y), f2bf(v.z), f2bf(v.w));
            *(ushort4*)((unsigned short*)(ws + OFF_EMBB) + gid * 4) = o;
        }
    } else if (b < PRO_PACK + PRO_EMB + PRO_STAT) {
        int bb = b - PRO_PACK - PRO_EMB;
        int type = bb >> 8, xb = bb & 255;
        const float* x = type ? A.ft_user : A.ft_item;
        int N = type ? N_USER : N_ITEM;
        float* sum = (float*)(ws + OFF_STATS) + type * 256;
        float* sq  = sum + 128;
        int c = tid & 127;
        int half = tid >> 7;
        float s = 0.f, s2 = 0.f;
        for (int r = xb * 2 + half; r < N; r += 512) {
            float v = x[(size_t)r * 128 + c];
            s += v; s2 += v * v;
        }
        ls[tid] = s; ls2[tid] = s2;
        __syncthreads();
        if (half == 0) {
            atomicAdd(&sum[c], ls[c] + ls[c + 128]);
            atomicAdd(&sq[c],  ls2[c] + ls2[c + 128]);
        }
    } else {
        int e = (b - PRO_PACK - PRO_EMB - PRO_STAT) * 256 + tid;
        if (e < EALL) {
            int dst = (e < E1N) ? A.vid1[e] : A.vid2[e - E1N];
            atomicAdd((int*)(ws + OFF_HIST) + dst, 1);
        }
    }
}

// ---------------- scan_partial: per-1024-chunk exclusive scan --------------
__global__ __launch_bounds__(1024) void scan_partial(char* __restrict__ ws) {
    __shared__ int sd[1024];
    const int* hist = (const int*)(ws + OFF_HIST);
    int* start  = (int*)(ws + OFF_START);
    int* cursor = (int*)(ws + OFF_CURSOR);
    int* bsum   = (int*)(ws + OFF_BSUM);
    int t = threadIdx.x;
    int gid = blockIdx.x * 1024 + t;
    int v = hist[gid];
    sd[t] = v;
    __syncthreads();
    #pragma unroll
    for (int off = 1; off < 1024; off <<= 1) {
        int x = (t >= off) ? sd[t - off] : 0;
        __syncthreads();
        sd[t] += x;
        __syncthreads();
    }
    int ex = sd[t] - v;        // exclusive within chunk
    start[gid] = ex;
    cursor[gid] = ex;
    if (t == 1023) bsum[blockIdx.x] = sd[t];
}

// ---------------- mid: bn_finalize (block 0) + scan_top (block 1) ----------
__global__ __launch_bounds__(256) void mid(const float* __restrict__ g_i, const float* __restrict__ b_i,
                                           const float* __restrict__ g_u, const float* __restrict__ b_u,
                                           const float* __restrict__ ae1, const float* __restrict__ ae2,
                                           char* __restrict__ ws) {
    __shared__ int sd[128];
    int t = threadIdx.x;
    if (blockIdx.x == 0) {
        const float* stats = (const float*)(ws + OFF_STATS);
        float* scale = (float*)(ws + OFF_SCALE);
        float* M     = (float*)(ws + OFF_M);
        int type = t >> 7, c = t & 127;
        float N = type ? (float)N_USER : (float)N_ITEM;
        float su = stats[type * 256 + c];
        float sq = stats[type * 256 + 128 + c];
        float mu = su / N;
        float var = sq / N - mu * mu;
        float rstd = rsqrtf(var + 1e-5f);
        float g = type ? g_u[c] : g_i[c];
        float b = type ? b_u[c] : b_i[c];
        scale[type * 256 + c]       = g * rstd;
        scale[type * 256 + 128 + c] = b - mu * g * rstd;
        if (t < 8) {
            float m1 = 0.f, m2 = 0.f;
            for (int j = 0; j < 16; j++) {
                m1 += fmaxf(ae1[t * 16 + j], 0.f);
                m2 += fmaxf(ae2[t * 16 + j], 0.f);
            }
            M[t] = fmaxf(m1, m2);   // uniform per-head shift, both etypes
        }
    } else {
        int* bsum = (int*)(ws + OFF_BSUM);
        int v = 0;
        if (t < 128) { v = (t < 98) ? bsum[t] : 0; sd[t] = v; }
        __syncthreads();
        #pragma unroll
        for (int off = 1; off < 128; off <<= 1) {
            int x = 0;
            if (t < 128 && t >= off) x = sd[t - off];
            __syncthreads();
            if (t < 128) sd[t] += x;
            __syncthreads();
        }
        if (t < 98) bsum[t] = sd[t] - v;   // exclusive chunk offsets
    }
}

// ---------------- edge scatter ---------------------------------------------
__global__ __launch_bounds__(256) void edge_scatter(const int* __restrict__ uid1, const int* __restrict__ vid1,
                                                    const int* __restrict__ cnt1,
                                                    const int* __restrict__ uid2, const int* __restrict__ vid2,
                                                    char* __restrict__ ws) {
    int e = blockIdx.x * 256 + threadIdx.x;
    if (e >= EALL) return;
    int* cursor = (int*)(ws + OFF_CURSOR);
    const int* bsum = (const int*)(ws + OFF_BSUM);
    int2* ord = (int2*)(ws + OFF_ORD);
    int2 rec; int dst;
    if (e < E1N) {
        rec.x = uid1[e]; rec.y = cnt1[e]; dst = vid1[e];
    } else {
        int ee = e - E1N;
        rec.x = N_ITEM + uid2[ee]; rec.y = -1; dst = vid2[ee];
    }
    int pos = atomicAdd(&cursor[dst], 1) + bsum[dst >> 10];
    ord[pos] = rec;
}

// ---------------- transform: 32 rows/wave, LDS-staged coalesced stores -----
// D[n][row] = sum_k W[n][k]*x[row][k]; A-op = packed W, B-op = BN'd x rows.
struct TArgs {
    const float* x;              // raw f32 features
    const float* bias0;          // bias for matrix 0 (q), may be null
    int N;
    int scaleOff;                // 0 item, 256 user
    int nmat;
    int wtIdx[5];
    unsigned short* out[5];
};

#define TB_I 782   // ceil(100000/128)
#define TB_U 391   // ceil(50000/128)
#define SPITCH 136

__global__ __launch_bounds__(256, 5) void transform(TArgs AI, TArgs AU, char* __restrict__ ws) {
    __shared__ unsigned short stg[4][2][16 * SPITCH];
    int b = blockIdx.x;
    const TArgs& A = (b < TB_I) ? AI : AU;
    int blk = (b < TB_I) ? b : b - TB_I;

    const unsigned short* wpack = (const unsigned short*)(ws + OFF_WPACK);
    const float* scaleb = (const float*)(ws + OFF_SCALE) + A.scaleOff;
    int tid = threadIdx.x, lane = tid & 63, wv = tid >> 6;
    int l16 = lane & 15, quad = lane >> 4;
    int base = blk * 128 + wv * 32;

    // B-fragments: BN-applied feature rows (bf16), zero-padded beyond N
    bf16x8 bfr[2][4];
    #pragma unroll
    for (int kt = 0; kt < 4; kt++) {
        int c0 = kt * 32 + quad * 8;
        float4 sc0 = *(const float4*)(scaleb + c0);
        float4 sc1 = *(const float4*)(scaleb + c0 + 4);
        float4 bi0 = *(const float4*)(scaleb + 128 + c0);
        float4 bi1 = *(const float4*)(scaleb + 128 + c0 + 4);
        #pragma unroll
        for (int it = 0; it < 2; it++) {
            int gr = base + it * 16 + l16;
            bf16x8 f = {0, 0, 0, 0, 0, 0, 0, 0};
            if (gr < A.N) {
                const float* p = A.x + (size_t)gr * 128 + c0;
                float4 v0 = *(const float4*)p;
                float4 v1 = *(const float4*)(p + 4);
                f[0] = (short)f2bf(fmaf(v0.x, sc0.x, bi0.x));
                f[1] = (short)f2bf(fmaf(v0.y, sc0.y, bi0.y));
                f[2] = (short)f2bf(fmaf(v0.z, sc0.z, bi0.z));
                f[3] = (short)f2bf(fmaf(v0.w, sc0.w, bi0.w));
                f[4] = (short)f2bf(fmaf(v1.x, sc1.x, bi1.x));
                f[5] = (short)f2bf(fmaf(v1.y, sc1.y, bi1.y));
                f[6] = (short)f2bf(fmaf(v1.z, sc1.z, bi1.z));
                f[7] = (short)f2bf(fmaf(v1.w, sc1.w, bi1.w));
            }
            bfr[it][kt] = f;
        }
    }

    for (int m = 0; m < A.nmat; m++) {
        const unsigned short* wp = wpack + (size_t)A.wtIdx[m] * 16384;
        unsigned short* outp = A.out[m];
        const float* bias = (m == 0) ? A.bias0 : nullptr;
        #pragma unroll
        for (int it = 0; it < 2; it++) {
            unsigned short* st = stg[wv][it];
            #pragma unroll
            for (int nt = 0; nt < 8; nt++) {
                bf16x8 a4[4];
                #pragma unroll
                for (int kt = 0; kt < 4; kt++)
                    a4[kt] = *(const bf16x8*)(wp + (size_t)((nt * 4 + kt) * 64 + lane) * 8);
                f32x4 acc = {0.f, 0.f, 0.f, 0.f};
                if (bias) {
                    float4 bv = *(const float4*)(bias + nt * 16 + quad * 4);
                    acc[0] = bv.x; acc[1] = bv.y; acc[2] = bv.z; acc[3] = bv.w;
                }
                #pragma unroll
                for (int kt = 0; kt < 4; kt++)
                    acc = __builtin_amdgcn_mfma_f32_16x16x32_bf16(a4[kt], bfr[it][kt], acc, 0, 0, 0);
                ushort4 o = make_ushort4(f2bf(acc[0]), f2bf(acc[1]), f2bf(acc[2]), f2bf(acc[3]));
                *(ushort4*)(st + l16 * SPITCH + nt * 16 + quad * 4) = o;
            }
            // wave-synchronous readback -> coalesced stores (no __syncthreads)
            #pragma unroll
            for (int i = 0; i < 4; i++) {
                int chunk = i * 64 + lane;
                int row = chunk >> 4, c8 = (chunk & 15) * 8;
                int gr = base + it * 16 + row;
                if (gr < A.N)
                    *(bf16x8*)(outp + (size_t)gr * 128 + c8) = *(const bf16x8*)(st + row * SPITCH + c8);
            }
        }
    }
}

// ---------------- fused edge phase: wave per dst, 2 slots, ord prefetch ----
__global__ __launch_bounds__(256, 8) void edge_agg(const float* __restrict__ ae1, const float* __restrict__ ae2,
                                                   char* __restrict__ ws) {
    const unsigned short* qc = (const unsigned short*)(ws + OFF_QC);
    const unsigned short* vc = (const unsigned short*)(ws + OFF_VC);
    const unsigned short* k1 = (const unsigned short*)(ws + OFF_K1);
    const unsigned short* k2 = (const unsigned short*)(ws + OFF_K2);
    const unsigned short* embb = (const unsigned short*)(ws + OFF_EMBB);
    const int* start = (const int*)(ws + OFF_START);
    const int* bsum  = (const int*)(ws + OFF_BSUM);
    const int2* ord = (const int2*)(ws + OFF_ORD);
    const float* M = (const float*)(ws + OFF_M);
    float* agg = (float*)(ws + OFF_AGG);

    int tid = threadIdx.x;
    int lane = tid & 63;
    int half = lane >> 5;     // edge slot within wave
    int l = lane & 31;
    int d0 = l << 2;          // 4 dims per lane
    int h = l >> 2;           // head
    int dst = blockIdx.x * 4 + (tid >> 6);
    if (dst >= N_ITEM) return;

    float mh = M[h];
    float4 ae1v = *(const float4*)(ae1 + d0);
    float4 ae2v = *(const float4*)(ae2 + d0);
    ushort4 k1p = *(const ushort4*)(k1 + (size_t)dst * 128 + d0);
    ushort4 k2p = *(const ushort4*)(k2 + (size_t)dst * 128 + d0);
    float4 k1v = make_float4(bf2f(k1p.x), bf2f(k1p.y), bf2f(k1p.z), bf2f(k1p.w));
    float4 k2v = make_float4(bf2f(k2p.x), bf2f(k2p.y), bf2f(k2p.z), bf2f(k2p.w));

    int beg = start[dst] + bsum[dst >> 10];
    int end = start[dst + 1] + bsum[(dst + 1) >> 10];
    float a0 = 0.f, a1 = 0.f, a2 = 0.f, a3 = 0.f, s = 0.f;

    int i = beg + half;
    if (i < end) {
        int2 rec = ord[i];
        while (true) {
            int inext = i + 2;
            int ipf = (inext < end) ? inext : (end - 1);
            int2 recn = ord[ipf];                     // prefetch next record
            bool t1 = rec.y >= 0;
            ushort4 qp = *(const ushort4*)(qc + (size_t)rec.x * 128 + d0);
            ushort4 vp = *(const ushort4*)(vc + (size_t)rec.x * 128 + d0);
            ushort4 ep = *(const ushort4*)(embb + (size_t)(t1 ? rec.y : 0) * 128 + d0);
            float x0 = bf2f(qp.x) + (t1 ? k1v.x + bf2f(ep.x) : k2v.x);
            float x1 = bf2f(qp.y) + (t1 ? k1v.y + bf2f(ep.y) : k2v.y);
            float x2 = bf2f(qp.z) + (t1 ? k1v.z + bf2f(ep.z) : k2v.z);
            float x3 = bf2f(qp.w) + (t1 ? k1v.w + bf2f(ep.w) : k2v.w);
            float4 ae = t1 ? ae1v : ae2v;
            float t = ae.x * __builtin_amdgcn_rcpf(1.f + __expf(-x0))
                    + ae.y * __builtin_amdgcn_rcpf(1.f + __expf(-x1))
                    + ae.z * __builtin_amdgcn_rcpf(1.f + __expf(-x2))
                    + ae.w * __builtin_amdgcn_rcpf(1.f + __expf(-x3));
            t += __shfl_xor(t, 1);
            t += __shfl_xor(t, 2);
            float ex = __expf(t - mh);
            s += ex;
            a0 = fmaf(ex, bf2f(vp.x), a0);
            a1 = fmaf(ex, bf2f(vp.y), a1);
            a2 = fmaf(ex, bf2f(vp.z), a2);
            a3 = fmaf(ex, bf2f(vp.w), a3);
            if (inext >= end) break;
            i = inext; rec = recn;
        }
    }
    // combine the two half-wave edge streams
    s  += __shfl_xor(s, 32);
    a0 += __shfl_xor(a0, 32);
    a1 += __shfl_xor(a1, 32);
    a2 += __shfl_xor(a2, 32);
    a3 += __shfl_xor(a3, 32);
    if (half == 0) {
        float inv = (s > 0.f) ? __builtin_amdgcn_rcpf(s) : 0.f;
        float4 o = make_float4(a0 * inv, a1 * inv, a2 * inv, a3 * inv);
        *(float4*)(agg + (size_t)dst * 128 + d0) = o;
    }
}

// ---------------- final: relu(agg @ Wagg.T + b + selfterm), LDS-staged -----
#define FPITCH 132

__global__ __launch_bounds__(256) void final_mfma(const float* __restrict__ b_agg,
                                                  float* __restrict__ out, char* __restrict__ ws) {
    __shared__ float stg[4][16 * FPITCH];
    const float* agg = (const float*)(ws + OFF_AGG);
    const unsigned short* selft = (const unsigned short*)(ws + OFF_SELF);
    const unsigned short* wp = (const unsigned short*)(ws + OFF_WPACK) + 7ull * 16384;
    int tid = threadIdx.x, lane = tid & 63, wv = tid >> 6;
    int l16 = lane & 15, quad = lane >> 4;
    int base = blockIdx.x * 256 + wv * 64;
    float* st = stg[wv];

    // B-fragments from agg rows (f32 -> bf16)
    bf16x8 bfr[4][4];
    #pragma unroll
    for (int it = 0; it < 4; it++) {
        int gr = base + it * 16 + l16;
        #pragma unroll
        for (int kt = 0; kt < 4; kt++) {
            bf16x8 f = {0, 0, 0, 0, 0, 0, 0, 0};
            if (gr < N_ITEM) {
                const float* p = agg + (size_t)gr * 128 + kt * 32 + quad * 8;
                float4 v0 = *(const float4*)p;
                float4 v1 = *(const float4*)(p + 4);
                f[0] = (short)f2bf(v0.x); f[1] = (short)f2bf(v0.y);
                f[2] = (short)f2bf(v0.z); f[3] = (short)f2bf(v0.w);
                f[4] = (short)f2bf(v1.x); f[5] = (short)f2bf(v1.y);
                f[6] = (short)f2bf(v1.z); f[7] = (short)f2bf(v1.w);
            }
            bfr[it][kt] = f;
        }
    }

    #pragma unroll
    for (int it = 0; it < 4; it++) {
        #pragma unroll
        for (int nt = 0; nt < 8; nt++) {
            bf16x8 a4[4];
            #pragma unroll
            for (int kt = 0; kt < 4; kt++)
                a4[kt] = *(const bf16x8*)(wp + (size_t)((nt * 4 + kt) * 64 + lane) * 8);
            float4 bv = *(const float4*)(b_agg + nt * 16 + quad * 4);
            f32x4 acc = {bv.x, bv.y, bv.z, bv.w};
            #pragma unroll
            for (int kt = 0; kt < 4; kt++)
                acc = __builtin_amdgcn_mfma_f32_16x16x32_bf16(a4[kt], bfr[it][kt], acc, 0, 0, 0);
            *(f32x4*)(st + l16 * FPITCH + nt * 16 + quad * 4) = acc;
        }
        // wave-synchronous readback: coalesced add-self + relu + store
        #pragma unroll
        for (int i = 0; i < 8; i++) {
            int chunk = i * 64 + lane;
            int row = chunk >> 5, c4 = (chunk & 31) * 4;
            int gr = base + it * 16 + row;
            if (gr < N_ITEM) {
                float4 v = *(const float4*)(st + row * FPITCH + c4);
                size_t idx = (size_t)gr * 128 + c4;
                ushort4 sf = *(const ushort4*)(selft + idx);
                float4 o;
                o.x = fmaxf(v.x + bf2f(sf.x), 0.f);
                o.y = fmaxf(v.y + bf2f(sf.y), 0.f);
                o.z = fmaxf(v.z + bf2f(sf.z), 0.f);
                o.w = fmaxf(v.w + bf2f(sf.w), 0.f);
                *(float4*)(out + idx) = o;
            }
        }
    }
}

// ---------------- host ----------------
extern "C" void kernel_launch(void* const* d_in, const int* in_sizes, int n_in,
                              void* d_out, int out_size, void* d_ws, size_t ws_size,
                              hipStream_t stream) {
    char* ws = (char*)d_ws;

    const float* ft_item = (const float*)d_in[0];
    const float* ft_user = (const float*)d_in[1];
    const float* bng_i = (const float*)d_in[2];
    const float* bnb_i = (const float*)d_in[3];
    const float* bng_u = (const float*)d_in[4];
    const float* bnb_u = (const float*)d_in[5];
    const float* Wq1 = (const float*)d_in[6];
    const float* bq1 = (const float*)d_in[7];
    const float* Wk1 = (const float*)d_in[8];
    const float* Wv1 = (const float*)d_in[9];
    const float* ae1 = (const float*)d_in[10];
    const float* emb = (const float*)d_in[11];
    const float* Wq2 = (const float*)d_in[12];
    const float* bq2 = (const float*)d_in[13];
    const float* Wk2 = (const float*)d_in[14];
    const float* Wv2 = (const float*)d_in[15];
    const float* ae2 = (const float*)d_in[16];
    const float* W_agg = (const float*)d_in[17];
    const float* b_agg = (const float*)d_in[18];
    const float* W_self = (const float*)d_in[19];
    const int* uid1 = (const int*)d_in[20];
    const int* vid1 = (const int*)d_in[21];
    const int* cnt1 = (const int*)d_in[22];
    const int* uid2 = (const int*)d_in[23];
    const int* vid2 = (const int*)d_in[24];
    float* out = (float*)d_out;

    // single memset: stats (2KB) + hist (adjacent)
    hipMemsetAsync(ws + OFF_STATS, 0, 2048 + (size_t)NPAD * 4, stream);

    // 1. prologue: pack weights + emb->bf16 + BN stats + dst histogram
    ProArgs pa;
    pa.w[0] = Wq1; pa.w[1] = Wk1; pa.w[2] = Wv1; pa.w[3] = Wk2;
    pa.w[4] = W_self; pa.w[5] = Wq2; pa.w[6] = Wv2; pa.w[7] = W_agg;
    pa.ft_item = ft_item; pa.ft_user = ft_user; pa.emb = emb;
    pa.vid1 = vid1; pa.vid2 = vid2;
    prologue<<<PRO_PACK + PRO_EMB + PRO_STAT + PRO_HIST, 256, 0, stream>>>(pa, ws);

    // 2. per-chunk exclusive scan
    scan_partial<<<98, 1024, 0, stream>>>(ws);

    // 3. BN finalize + chunk-offset scan
    mid<<<2, 256, 0, stream>>>(bng_i, bnb_i, bng_u, bnb_u, ae1, ae2, ws);

    // 4. edge scatter (CSR records)
    edge_scatter<<<(EALL + 255) / 256, 256, 0, stream>>>(uid1, vid1, cnt1, uid2, vid2, ws);

    // 5. all 7 node-transform GEMMs (item range + user range)
    TArgs ti, tu;
    ti.x = ft_item; ti.bias0 = bq1; ti.N = N_ITEM; ti.scaleOff = 0; ti.nmat = 5;
    ti.wtIdx[0] = 0; ti.wtIdx[1] = 1; ti.wtIdx[2] = 2; ti.wtIdx[3] = 3; ti.wtIdx[4] = 4;
    unsigned short* QC = (unsigned short*)(ws + OFF_QC);
    unsigned short* VC = (unsigned short*)(ws + OFF_VC);
    ti.out[0] = QC;
    ti.out[1] = (unsigned short*)(ws + OFF_K1);
    ti.out[2] = VC;
    ti.out[3] = (unsigned short*)(ws + OFF_K2);
    ti.out[4] = (unsigned short*)(ws + OFF_SELF);
    tu.x = ft_user; tu.bias0 = bq2; tu.N = N_USER; tu.scaleOff = 256; tu.nmat = 2;
    tu.wtIdx[0] = 5; tu.wtIdx[1] = 6; tu.wtIdx[2] = 0; tu.wtIdx[3] = 0; tu.wtIdx[4] = 0;
    tu.out[0] = QC + (size_t)N_ITEM * 128;
    tu.out[1] = VC + (size_t)N_ITEM * 128;
    tu.out[2] = tu.out[3] = tu.out[4] = tu.out[0];
    transform<<<TB_I + TB_U, 256, 0, stream>>>(ti, tu, ws);

    // 6. fused edge softmax+aggregate
    edge_agg<<<(N_ITEM + 3) / 4, 256, 0, stream>>>(ae1, ae2, ws);

    // 7. final GEMM + self + relu
    final_mfma<<<(N_ITEM + 255) / 256, 256, 0, stream>>>(b_agg, out, ws);
}